// Round 5
// baseline (257.535 us; speedup 1.0000x reference)
//
#include <hip/hip_runtime.h>
#include <hip/hip_cooperative_groups.h>
#include <stdint.h>

namespace cg = cooperative_groups;

#define NTOK 1536
#define CDIM 768
#define NH 8
#define DKH 64
#define DVH 96
#define NF 96

typedef unsigned short u16;
typedef __attribute__((ext_vector_type(8))) short s16x8;   // 8 bf16 (4 VGPRs)
typedef __attribute__((ext_vector_type(4))) float f32x4;   // MFMA acc

__device__ __forceinline__ float b2f(u16 u) {
    union { uint32_t i; float f; } v; v.i = ((uint32_t)u) << 16; return v.f;
}
__device__ __forceinline__ u16 f2b(float f) {
    union { float f; uint32_t i; } v; v.f = f;
    uint32_t x = v.i;
    return (u16)((x + 0x7FFFu + ((x >> 16) & 1u)) >> 16);
}
__device__ __forceinline__ float ldin(const void* p, int i, int f32) {
    return f32 ? ((const float*)p)[i] : b2f(((const u16*)p)[i]);
}

// Inline wave-uniform dtype probe: scans first 256 u16 words.  A true-bf16
// buffer never decodes |v|>=1e6; fp32 mantissa-low words do w.p. ~0.42 each
// (~128 of the 256 samples) -> miss prob ~3e-29.  Returns 1 iff fp32.
__device__ __forceinline__ int probe_f32(const void* p) {
    const u16* a = (const u16*)p;
    int lane = threadIdx.x & 63;
    int bad = 0;
#pragma unroll
    for (int t = 0; t < 4; ++t) {
        float v = b2f(a[lane + t * 64]);
        if (!(fabsf(v) < 1e6f)) bad = 1;
    }
    return __ballot(bad) != 0ull;
}

// Fragment-major: element (m, kk) of a (16 x 32k) 512-elem block sits at
// ((kk>>3)*16 + m)*8 + (kk&7)  == lane*8 + slot.
#define FIDX(m, kk) ((((kk) >> 3) * 16 + (m)) * 8 + ((kk) & 7))

// ---------------------------------------------------------------------------
// ws layout (float offsets). ~14.8 MB.
// ---------------------------------------------------------------------------
#define OFF_WSUF 16
#define OFF_S11  (OFF_WSUF + 5632)
#define OFF_QF   (OFF_S11 + 147456)     // u16: qfrag  (h,ti:96,kc2:2)  A-frags
#define OFF_KF   (OFF_QF + 393216)      // u16: kfrag  (h,tj:96,kc2:2)  B-frags
#define OFF_VF   (OFF_KF + 393216)      // u16: vfrag  (h,jc:48,nt:6)   B-frags
#define OFF_AOF  (OFF_VF + 589824)      // u16: aofrag (ti:96,kc:24)    A-frags
#define OFF_XF   (OFF_AOF + 589824)     // u16: xfrag  (ti:96,kc:24)    A-frags
#define OFF_WF   (OFF_XF + 589824)      // u16: wfrag  (tn:112,kc:24)   B-frags
#define OFF_WOF  (OFF_WF + 688128)      // u16: wofrag (tn:48,kc:24)    B-frags

// ---------------------------------------------------------------------------
// Kernel PR: build fragment buffers.  NO LDS, NO barriers, high MLP.
// (R0-proven version, verbatim.)
// ---------------------------------------------------------------------------
__global__ __launch_bounds__(256) void prep(const void* __restrict__ x,
                                            const void* __restrict__ Wq,
                                            const void* __restrict__ Wk,
                                            const void* __restrict__ Wv,
                                            const void* __restrict__ Wout,
                                            const void* __restrict__ Wpos,
                                            float* __restrict__ ws) {
    int bx = blockIdx.x, tid = threadIdx.x;
    int wv = tid >> 6, L = tid & 63;

    if (bx < 144) {
        int f = probe_f32(x);
        u16* dst = (u16*)(ws + OFF_XF);
        int cbase = (bx * 4 + wv) * 4;
        int m = L & 15, kq = L >> 4;
        int srcs[4];
#pragma unroll
        for (int c = 0; c < 4; ++c) {
            int ch = cbase + c;
            int ti = ch / 24, kc = ch % 24;
            srcs[c] = (ti * 16 + m) * CDIM + kc * 32 + kq * 8;
        }
        if (f) {
            float4 a[4][2];
#pragma unroll
            for (int c = 0; c < 4; ++c) {
                const float* xp = (const float*)x + srcs[c];
                a[c][0] = *(const float4*)(xp);
                a[c][1] = *(const float4*)(xp + 4);
            }
#pragma unroll
            for (int c = 0; c < 4; ++c) {
                union { u16 u[8]; uint4 v; } pk;
                pk.u[0] = f2b(a[c][0].x); pk.u[1] = f2b(a[c][0].y);
                pk.u[2] = f2b(a[c][0].z); pk.u[3] = f2b(a[c][0].w);
                pk.u[4] = f2b(a[c][1].x); pk.u[5] = f2b(a[c][1].y);
                pk.u[6] = f2b(a[c][1].z); pk.u[7] = f2b(a[c][1].w);
                *(uint4*)(dst + (cbase + c) * 512 + L * 8) = pk.v;
            }
        } else {
            uint4 v[4];
#pragma unroll
            for (int c = 0; c < 4; ++c) v[c] = *(const uint4*)((const u16*)x + srcs[c]);
#pragma unroll
            for (int c = 0; c < 4; ++c)
                *(uint4*)(dst + (cbase + c) * 512 + L * 8) = v[c];
        }
        return;
    }
    if (bx < 1104) {
        int c = (bx - 144) * 4 + wv;
        const void* src; int ld, cn0; u16* dst; int kc;
        if (c < 2688) {
            int tn = c / 24; kc = c % 24;
            int n0 = tn * 16;
            dst = (u16*)(ws + OFF_WF) + c * 512;
            if (n0 < 512)       { src = Wq; ld = 512;  cn0 = n0; }
            else if (n0 < 1024) { src = Wk; ld = 512;  cn0 = n0 - 512; }
            else                { src = Wv; ld = CDIM; cn0 = n0 - 1024; }
        } else {
            int c2 = c - 2688;
            int tn = c2 / 24; kc = c2 % 24;
            dst = (u16*)(ws + OFF_WOF) + c2 * 512;
            src = Wout; ld = CDIM; cn0 = tn * 16;
        }
        int f = probe_f32(src);
        int nn = L & 15, kq = L >> 4;
        int base = (kc * 32 + kq * 8) * ld + cn0 + nn;
        union { u16 u[8]; uint4 v; } pk;
        if (f) {
            const float* sp = (const float*)src + base;
            float a0 = sp[0], a1 = sp[ld], a2 = sp[2 * ld], a3 = sp[3 * ld];
            float a4 = sp[4 * ld], a5 = sp[5 * ld], a6 = sp[6 * ld], a7 = sp[7 * ld];
            pk.u[0] = f2b(a0); pk.u[1] = f2b(a1); pk.u[2] = f2b(a2); pk.u[3] = f2b(a3);
            pk.u[4] = f2b(a4); pk.u[5] = f2b(a5); pk.u[6] = f2b(a6); pk.u[7] = f2b(a7);
        } else {
            const u16* sp = (const u16*)src + base;
            pk.u[0] = sp[0]; pk.u[1] = sp[ld]; pk.u[2] = sp[2 * ld]; pk.u[3] = sp[3 * ld];
            pk.u[4] = sp[4 * ld]; pk.u[5] = sp[5 * ld]; pk.u[6] = sp[6 * ld]; pk.u[7] = sp[7 * ld];
        }
        *(uint4*)(dst + L * 8) = pk.v;
        return;
    }
    // ---- wsuf ----
    int t = bx - 1104;
    int f = probe_f32(Wpos);
    for (int hd = tid; hd < 512; hd += 256) {
        float s0 = 0.f, s1 = 0.f, s2 = 0.f, s3 = 0.f;
        int f0 = t;
        for (; f0 + 4 <= NF; f0 += 4) {
            s0 += ldin(Wpos, f0 * 512 + hd, f);
            s1 += ldin(Wpos, (f0 + 1) * 512 + hd, f);
            s2 += ldin(Wpos, (f0 + 2) * 512 + hd, f);
            s3 += ldin(Wpos, (f0 + 3) * 512 + hd, f);
        }
        for (; f0 < NF; ++f0) s0 += ldin(Wpos, f0 * 512 + hd, f);
        ws[OFF_WSUF + t * 512 + hd] = (s0 + s1) + (s2 + s3);
    }
}

// ---------------------------------------------------------------------------
// Kernel 1: QKV GEMM, register-direct MFMA (R0-proven version, verbatim).
// ---------------------------------------------------------------------------
__global__ __launch_bounds__(256) void qkv_reg(const void* __restrict__ rcb,
                                               const void* __restrict__ rpb,
                                               float* __restrict__ ws) {
    __shared__ float qt[64 * 68];
    __shared__ float rpd[12];
    const u16* xf = (const u16*)(ws + OFF_XF);
    const u16* wf = (const u16*)(ws + OFF_WF);
    u16* qf = (u16*)(ws + OFF_QF);
    u16* kf = (u16*)(ws + OFF_KF);
    u16* vf = (u16*)(ws + OFF_VF);

    int tid = threadIdx.x;
    int lane = tid & 63, w = tid >> 6;
    int quad = lane >> 4, col = lane & 15;
    int ti4 = blockIdx.x;
    int tn4 = blockIdx.y;
    int tn = tn4 * 4 + w;
    int i0 = ti4 * 64;
    bool isQ = (tn4 < 8);
    int hq = tn4;

    s16x8 bw0, bw1;
    int f32p = 0, f32c = 0;
    if (isQ) {
        f32p = probe_f32(rpb);
        f32c = probe_f32(rcb);
        int t = lane & 15, kq = lane >> 4;
        union { u16 u[8]; s16x8 v; } p0, p1;
#pragma unroll
        for (int j = 0; j < 8; ++j) {
            float v0 = 0.f, v1 = 0.f;
            if (t < 11) {
                v0 = ws[OFF_WSUF + t * 512 + hq * 64 + kq * 8 + j];
                v1 = ws[OFF_WSUF + t * 512 + hq * 64 + 32 + kq * 8 + j];
            }
            p0.u[j] = f2b(v0); p1.u[j] = f2b(v1);
        }
        bw0 = p0.v; bw1 = p1.v;
        if (tid < 12) {
            float s = 0.f;
            if (tid < 11) {
                const float* wp = ws + OFF_WSUF + tid * 512 + hq * 64;
                for (int d = 0; d < 64; ++d) s += ldin(rpb, hq * 64 + d, f32p) * wp[d];
            }
            rpd[tid] = s;
        }
    }

    f32x4 acc[4];
#pragma unroll
    for (int mt = 0; mt < 4; ++mt) acc[mt] = (f32x4){0.f, 0.f, 0.f, 0.f};

    const u16* bp = wf + (tn * 24) * 512 + lane * 8;
    const u16* ap = xf + (ti4 * 4 * 24) * 512 + lane * 8;
#pragma unroll 4
    for (int kc = 0; kc < 24; ++kc) {
        s16x8 bfrag = *(const s16x8*)(bp + kc * 512);
#pragma unroll
        for (int mt = 0; mt < 4; ++mt) {
            s16x8 afrag = *(const s16x8*)(ap + (mt * 24 + kc) * 512);
            acc[mt] = __builtin_amdgcn_mfma_f32_16x16x32_bf16(afrag, bfrag, acc[mt], 0, 0, 0);
        }
    }

    if (isQ) {
#pragma unroll
        for (int mt = 0; mt < 4; ++mt)
#pragma unroll
            for (int r = 0; r < 4; ++r)
                qt[(mt * 16 + quad * 4 + r) * 68 + w * 16 + col] = acc[mt][r] * 0.125f;
        __syncthreads();
        int m = lane & 15, kq = lane >> 4;
#pragma unroll
        for (int kc2 = 0; kc2 < 2; ++kc2) {
            union { u16 u[8]; uint4 v; } pk;
#pragma unroll
            for (int j = 0; j < 8; ++j) {
                int d = kc2 * 32 + kq * 8 + j;
                pk.u[j] = f2b(qt[(w * 16 + m) * 68 + d] + ldin(rcb, hq * 64 + d, f32c));
            }
            *(uint4*)(qf + (((hq * 96 + ti4 * 4 + w) * 2 + kc2) * 512) + lane * 8) = pk.v;
        }
        union { u16 u[8]; s16x8 v; } qa0, qa1;
#pragma unroll
        for (int j = 0; j < 8; ++j) {
            qa0.u[j] = f2b(qt[(w * 16 + m) * 68 + kq * 8 + j]);
            qa1.u[j] = f2b(qt[(w * 16 + m) * 68 + 32 + kq * 8 + j]);
        }
        f32x4 s11a = (f32x4){0.f, 0.f, 0.f, 0.f};
        s11a = __builtin_amdgcn_mfma_f32_16x16x32_bf16(qa0.v, bw0, s11a, 0, 0, 0);
        s11a = __builtin_amdgcn_mfma_f32_16x16x32_bf16(qa1.v, bw1, s11a, 0, 0, 0);
        if (col < 12) {
            float rp = rpd[col];
            float* s11 = ws + OFF_S11;
#pragma unroll
            for (int r = 0; r < 4; ++r)
                s11[(hq * NTOK + i0 + w * 16 + quad * 4 + r) * 12 + col] = s11a[r] + rp;
        }
    } else if (tn < 64) {
        int h = (tn >> 2) - 8;
        int d = ((tn & 3) * 16) + col;
#pragma unroll
        for (int mt = 0; mt < 4; ++mt) {
            int tj = ti4 * 4 + mt;
#pragma unroll
            for (int r = 0; r < 4; ++r) {
                int nn = quad * 4 + r;
                kf[((h * 96 + tj) * 2 + (d >> 5)) * 512 + FIDX(nn, d & 31)] = f2b(acc[mt][r]);
            }
        }
    } else {
        int c = tn * 16 + col - 1024;
        int h = c / 96, d = c % 96;
        int nt = d >> 4, nn = d & 15;
#pragma unroll
        for (int mt = 0; mt < 4; ++mt) {
#pragma unroll
            for (int r = 0; r < 4; ++r) {
                int j = i0 + mt * 16 + quad * 4 + r;
                int jc = j >> 5, kk = j & 31;
                vf[((h * 48 + jc) * 6 + nt) * 512 + FIDX(nn, kk)] = f2b(acc[mt][r]);
            }
        }
    }
}

// ---------------------------------------------------------------------------
// Kernel 3 (fallback): MFMA flash attention — exact R0 147us version.
// ---------------------------------------------------------------------------
__global__ __launch_bounds__(512) void attn_mfma(float* __restrict__ ws) {
    __shared__ float s11b[192];
    __shared__ alignas(16) u16 pbuf[8][16 * 36];
    __shared__ float Om[8][16 * 96];
    __shared__ float lw[8][16];

    const u16* qf = (const u16*)(ws + OFF_QF);
    const u16* kf = (const u16*)(ws + OFF_KF);
    const u16* vf = (const u16*)(ws + OFF_VF);
    const float* s11 = ws + OFF_S11;
    u16* aof = (u16*)(ws + OFF_AOF);

    int h = blockIdx.x & 7;               // XCD-affine
    int ti = blockIdx.x >> 3;
    int i0 = ti * 16;
    int tid = threadIdx.x;
    int wv = tid >> 6, lane = tid & 63;
    int quad = lane >> 4, col = lane & 15;

    if (tid < 192) s11b[tid] = s11[(h * NTOK + i0 + tid / 12) * 12 + tid % 12];
    const u16* qp = qf + ((h * 96 + ti) * 2) * 512 + lane * 8;
    s16x8 a_lo = *(const s16x8*)(qp);
    s16x8 a_hi = *(const s16x8*)(qp + 512);
    __syncthreads();

    f32x4 O[6];
    float lsum[4];
#pragma unroll
    for (int nt = 0; nt < 6; ++nt) O[nt] = (f32x4){0.f, 0.f, 0.f, 0.f};
#pragma unroll
    for (int r = 0; r < 4; ++r) lsum[r] = 0.f;

    const u16* kbase = kf + ((h * 96 + wv * 12) * 2) * 512 + lane * 8;
    s16x8 k0lo = *(const s16x8*)(kbase);
    s16x8 k0hi = *(const s16x8*)(kbase + 512);
    s16x8 k1lo = *(const s16x8*)(kbase + 1024);
    s16x8 k1hi = *(const s16x8*)(kbase + 1536);

    for (int c = 0; c < 6; ++c) {
        f32x4 t0 = (f32x4){0.f, 0.f, 0.f, 0.f};
        f32x4 t1 = (f32x4){0.f, 0.f, 0.f, 0.f};
        t0 = __builtin_amdgcn_mfma_f32_16x16x32_bf16(a_lo, k0lo, t0, 0, 0, 0);
        t0 = __builtin_amdgcn_mfma_f32_16x16x32_bf16(a_hi, k0hi, t0, 0, 0, 0);
        t1 = __builtin_amdgcn_mfma_f32_16x16x32_bf16(a_lo, k1lo, t1, 0, 0, 0);
        t1 = __builtin_amdgcn_mfma_f32_16x16x32_bf16(a_hi, k1hi, t1, 0, 0, 0);
        if (c < 5) {
            const u16* kn = kbase + (c + 1) * 2048;
            k0lo = *(const s16x8*)(kn);
            k0hi = *(const s16x8*)(kn + 512);
            k1lo = *(const s16x8*)(kn + 1024);
            k1hi = *(const s16x8*)(kn + 1536);
        }
        int j0 = wv * 192 + c * 32;
        int lo1 = j0 - (i0 + 15), lo2 = i0 - (j0 + 31);
        int dmin = lo1 > 0 ? lo1 : (lo2 > 0 ? lo2 : 0);
        int dm1 = i0 + 15 - j0, dm2 = j0 + 31 - i0;
        int dmax = dm1 > dm2 ? dm1 : dm2;
        int tlo = 31 - __builtin_clz(dmin + 1);
        int thi = 31 - __builtin_clz(dmax + 1);
        if (tlo == thi) {
#pragma unroll
            for (int r = 0; r < 4; ++r) {
                int row = quad * 4 + r;
                float bv = s11b[row * 12 + tlo] - 12.f;
                float p0 = __expf(t0[r] + bv);
                float p1 = __expf(t1[r] + bv);
                pbuf[wv][row * 36 + col] = f2b(p0);
                pbuf[wv][row * 36 + 16 + col] = f2b(p1);
                lsum[r] += p0 + p1;
            }
        } else {
#pragma unroll
            for (int r = 0; r < 4; ++r) {
                int row = quad * 4 + r;
                int ig = i0 + row;
                int d0 = ig - (j0 + col); d0 = d0 < 0 ? -d0 : d0;
                int d1 = ig - (j0 + 16 + col); d1 = d1 < 0 ? -d1 : d1;
                float v0 = t0[r] + s11b[row * 12 + (31 - __builtin_clz(d0 + 1))];
                float v1 = t1[r] + s11b[row * 12 + (31 - __builtin_clz(d1 + 1))];
                float p0 = __expf(v0 - 12.f);
                float p1 = __expf(v1 - 12.f);
                pbuf[wv][row * 36 + col] = f2b(p0);
                pbuf[wv][row * 36 + 16 + col] = f2b(p1);
                lsum[r] += p0 + p1;
            }
        }
        int jc = wv * 6 + c;
        const u16* pr = &pbuf[wv][col * 36 + quad * 8];
        union { s16x8 v; uint2 u2[2]; } pa;
        pa.u2[0] = *(const uint2*)(pr);
        pa.u2[1] = *(const uint2*)(pr + 4);
        const u16* vp = vf + ((h * 48 + jc) * 6) * 512 + lane * 8;
#pragma unroll
        for (int nt = 0; nt < 6; ++nt) {
            s16x8 vfr = *(const s16x8*)(vp + nt * 512);
            O[nt] = __builtin_amdgcn_mfma_f32_16x16x32_bf16(pa.v, vfr, O[nt], 0, 0, 0);
        }
    }

#pragma unroll
    for (int off = 1; off < 16; off <<= 1)
#pragma unroll
        for (int r = 0; r < 4; ++r) lsum[r] += __shfl_xor(lsum[r], off);
    if (col == 0)
#pragma unroll
        for (int r = 0; r < 4; ++r) lw[wv][quad * 4 + r] = lsum[r];
#pragma unroll
    for (int r = 0; r < 4; ++r) {
        int row = quad * 4 + r;
#pragma unroll
        for (int nt = 0; nt < 6; ++nt)
            Om[wv][row * 96 + nt * 16 + col] = O[nt][r];
    }
    __syncthreads();
    for (int idx = tid; idx < 16 * 96; idx += 512) {
        int row = idx / 96, cc = idx % 96;
        float L = 0.f, val = 0.f;
#pragma unroll
        for (int v = 0; v < 8; ++v) { L += lw[v][row]; val += Om[v][idx]; }
        aof[(ti * 24 + h * 3 + (cc >> 5)) * 512 + FIDX(row, cc & 31)] = f2b(val / L);
    }
}

// ---------------------------------------------------------------------------
// Kernel 4 (fallback): output GEMM (R0-proven version, verbatim).
// ---------------------------------------------------------------------------
__global__ __launch_bounds__(256) void out_reg(const void* __restrict__ bout,
                                               float* __restrict__ ws,
                                               float* __restrict__ out) {
    const u16* af = (const u16*)(ws + OFF_AOF);
    const u16* wof = (const u16*)(ws + OFF_WOF);
    int f32b = probe_f32(bout);

    int tid = threadIdx.x;
    int lane = tid & 63, w = tid >> 6;
    int quad = lane >> 4, col = lane & 15;
    int ti4 = blockIdx.x;
    int tn = blockIdx.y * 4 + w;
    int i0 = ti4 * 64;
    int n0 = blockIdx.y * 64;

    f32x4 acc[4];
#pragma unroll
    for (int mt = 0; mt < 4; ++mt) acc[mt] = (f32x4){0.f, 0.f, 0.f, 0.f};

    const u16* bp = wof + (tn * 24) * 512 + lane * 8;
    const u16* ap = af + (ti4 * 4 * 24) * 512 + lane * 8;
#pragma unroll 4
    for (int kc = 0; kc < 24; ++kc) {
        s16x8 bfrag = *(const s16x8*)(bp + kc * 512);
#pragma unroll
        for (int mt = 0; mt < 4; ++mt) {
            s16x8 afrag = *(const s16x8*)(ap + (mt * 24 + kc) * 512);
            acc[mt] = __builtin_amdgcn_mfma_f32_16x16x32_bf16(afrag, bfrag, acc[mt], 0, 0, 0);
        }
    }

    int c = n0 + w * 16 + col;
    float bias = ldin(bout, c, f32b);
#pragma unroll
    for (int mt = 0; mt < 4; ++mt) {
#pragma unroll
        for (int r = 0; r < 4; ++r) {
            int i = i0 + mt * 16 + quad * 4 + r;
            out[i * CDIM + c] = acc[mt][r] + bias;
        }
    }
}

// ---------------------------------------------------------------------------
// Fused attn+out (R1-verified: passed, <43us including grid sync).
// attn phase: 768 units; out phase: 288 units as two 256-thr halves.
// ---------------------------------------------------------------------------
__global__ __launch_bounds__(512) void fused_ao(const void* __restrict__ bout,
                                                float* __restrict__ ws,
                                                float* __restrict__ out) {
    __shared__ float s11b[192];
    __shared__ alignas(16) u16 pbuf[8][16 * 36];
    __shared__ float Om[8][16 * 96];
    __shared__ float lw[8][16];

    const u16* qf = (const u16*)(ws + OFF_QF);
    const u16* kf = (const u16*)(ws + OFF_KF);
    const u16* vf = (const u16*)(ws + OFF_VF);
    const float* s11 = ws + OFF_S11;
    u16* aof = (u16*)(ws + OFF_AOF);

    int tid = threadIdx.x;
    int wv = tid >> 6, lane = tid & 63;
    int quad = lane >> 4, col = lane & 15;

    // -------------------- phase 1: attn units (768) --------------------
    for (int u = blockIdx.x; u < 768; u += gridDim.x) {
        int h = u & 7;                // XCD-affine (preserved: (u+grid)&7 == u&7)
        int ti = u >> 3;
        int i0 = ti * 16;

        if (tid < 192) s11b[tid] = s11[(h * NTOK + i0 + tid / 12) * 12 + tid % 12];
        const u16* qp = qf + ((h * 96 + ti) * 2) * 512 + lane * 8;
        s16x8 a_lo = *(const s16x8*)(qp);
        s16x8 a_hi = *(const s16x8*)(qp + 512);
        __syncthreads();

        f32x4 O[6];
        float lsum[4];
#pragma unroll
        for (int nt = 0; nt < 6; ++nt) O[nt] = (f32x4){0.f, 0.f, 0.f, 0.f};
#pragma unroll
        for (int r = 0; r < 4; ++r) lsum[r] = 0.f;

        const u16* kbase = kf + ((h * 96 + wv * 12) * 2) * 512 + lane * 8;
        s16x8 k0lo = *(const s16x8*)(kbase);
        s16x8 k0hi = *(const s16x8*)(kbase + 512);
        s16x8 k1lo = *(const s16x8*)(kbase + 1024);
        s16x8 k1hi = *(const s16x8*)(kbase + 1536);

        for (int c = 0; c < 6; ++c) {
            f32x4 t0 = (f32x4){0.f, 0.f, 0.f, 0.f};
            f32x4 t1 = (f32x4){0.f, 0.f, 0.f, 0.f};
            t0 = __builtin_amdgcn_mfma_f32_16x16x32_bf16(a_lo, k0lo, t0, 0, 0, 0);
            t0 = __builtin_amdgcn_mfma_f32_16x16x32_bf16(a_hi, k0hi, t0, 0, 0, 0);
            t1 = __builtin_amdgcn_mfma_f32_16x16x32_bf16(a_lo, k1lo, t1, 0, 0, 0);
            t1 = __builtin_amdgcn_mfma_f32_16x16x32_bf16(a_hi, k1hi, t1, 0, 0, 0);
            if (c < 5) {
                const u16* kn = kbase + (c + 1) * 2048;
                k0lo = *(const s16x8*)(kn);
                k0hi = *(const s16x8*)(kn + 512);
                k1lo = *(const s16x8*)(kn + 1024);
                k1hi = *(const s16x8*)(kn + 1536);
            }
            int j0 = wv * 192 + c * 32;
            int lo1 = j0 - (i0 + 15), lo2 = i0 - (j0 + 31);
            int dmin = lo1 > 0 ? lo1 : (lo2 > 0 ? lo2 : 0);
            int dm1 = i0 + 15 - j0, dm2 = j0 + 31 - i0;
            int dmax = dm1 > dm2 ? dm1 : dm2;
            int tlo = 31 - __builtin_clz(dmin + 1);
            int thi = 31 - __builtin_clz(dmax + 1);
            if (tlo == thi) {
#pragma unroll
                for (int r = 0; r < 4; ++r) {
                    int row = quad * 4 + r;
                    float bv = s11b[row * 12 + tlo] - 12.f;
                    float p0 = __expf(t0[r] + bv);
                    float p1 = __expf(t1[r] + bv);
                    pbuf[wv][row * 36 + col] = f2b(p0);
                    pbuf[wv][row * 36 + 16 + col] = f2b(p1);
                    lsum[r] += p0 + p1;
                }
            } else {
#pragma unroll
                for (int r = 0; r < 4; ++r) {
                    int row = quad * 4 + r;
                    int ig = i0 + row;
                    int d0 = ig - (j0 + col); d0 = d0 < 0 ? -d0 : d0;
                    int d1 = ig - (j0 + 16 + col); d1 = d1 < 0 ? -d1 : d1;
                    float v0 = t0[r] + s11b[row * 12 + (31 - __builtin_clz(d0 + 1))];
                    float v1 = t1[r] + s11b[row * 12 + (31 - __builtin_clz(d1 + 1))];
                    float p0 = __expf(v0 - 12.f);
                    float p1 = __expf(v1 - 12.f);
                    pbuf[wv][row * 36 + col] = f2b(p0);
                    pbuf[wv][row * 36 + 16 + col] = f2b(p1);
                    lsum[r] += p0 + p1;
                }
            }
            int jc = wv * 6 + c;
            const u16* pr = &pbuf[wv][col * 36 + quad * 8];
            union { s16x8 v; uint2 u2[2]; } pa;
            pa.u2[0] = *(const uint2*)(pr);
            pa.u2[1] = *(const uint2*)(pr + 4);
            const u16* vp = vf + ((h * 48 + jc) * 6) * 512 + lane * 8;
#pragma unroll
            for (int nt = 0; nt < 6; ++nt) {
                s16x8 vfr = *(const s16x8*)(vp + nt * 512);
                O[nt] = __builtin_amdgcn_mfma_f32_16x16x32_bf16(pa.v, vfr, O[nt], 0, 0, 0);
            }
        }

#pragma unroll
        for (int off = 1; off < 16; off <<= 1)
#pragma unroll
            for (int r = 0; r < 4; ++r) lsum[r] += __shfl_xor(lsum[r], off);
        if (col == 0)
#pragma unroll
            for (int r = 0; r < 4; ++r) lw[wv][quad * 4 + r] = lsum[r];
#pragma unroll
        for (int r = 0; r < 4; ++r) {
            int row = quad * 4 + r;
#pragma unroll
            for (int nt = 0; nt < 6; ++nt)
                Om[wv][row * 96 + nt * 16 + col] = O[nt][r];
        }
        __syncthreads();
        for (int idx = tid; idx < 16 * 96; idx += 512) {
            int row = idx / 96, cc = idx % 96;
            float Ls = 0.f, val = 0.f;
#pragma unroll
            for (int v = 0; v < 8; ++v) { Ls += lw[v][row]; val += Om[v][idx]; }
            aof[(ti * 24 + h * 3 + (cc >> 5)) * 512 + FIDX(row, cc & 31)] = f2b(val / Ls);
        }
        __syncthreads();   // protect s11b/pbuf/Om/lw WAR across unit iterations
    }

    __threadfence();            // device-scope release of aof writes
    cg::this_grid().sync();

    // -------------------- phase 2: out units (288, two 256-thr halves) ----
    const u16* af = (const u16*)(ws + OFF_AOF);
    const u16* wof = (const u16*)(ws + OFF_WOF);
    int f32b = probe_f32(bout);
    int half = tid >> 8, t2 = tid & 255;

    for (int u = blockIdx.x * 2 + half; u < 288; u += gridDim.x * 2) {
        int ti4 = u % 24, by = u / 24;
        int lane2 = t2 & 63, w2 = t2 >> 6;
        int quad2 = lane2 >> 4, col2 = lane2 & 15;
        int tn = by * 4 + w2;
        int i0 = ti4 * 64;
        int n0 = by * 64;

        f32x4 acc[4];
#pragma unroll
        for (int mt = 0; mt < 4; ++mt) acc[mt] = (f32x4){0.f, 0.f, 0.f, 0.f};

        const u16* bp = wof + (tn * 24) * 512 + lane2 * 8;
        const u16* ap = af + (ti4 * 4 * 24) * 512 + lane2 * 8;
#pragma unroll 4
        for (int kc = 0; kc < 24; ++kc) {
            s16x8 bfrag = *(const s16x8*)(bp + kc * 512);
#pragma unroll
            for (int mt = 0; mt < 4; ++mt) {
                s16x8 afrag = *(const s16x8*)(ap + (mt * 24 + kc) * 512);
                acc[mt] = __builtin_amdgcn_mfma_f32_16x16x32_bf16(afrag, bfrag, acc[mt], 0, 0, 0);
            }
        }

        int c = n0 + w2 * 16 + col2;
        float bias = ldin(bout, c, f32b);
#pragma unroll
        for (int mt = 0; mt < 4; ++mt) {
#pragma unroll
            for (int r = 0; r < 4; ++r) {
                int i = i0 + mt * 16 + quad2 * 4 + r;
                out[i * CDIM + c] = acc[mt][r] + bias;
            }
        }
    }
}

// ---------------------------------------------------------------------------
extern "C" void kernel_launch(void* const* d_in, const int* in_sizes, int n_in,
                              void* d_out, int out_size, void* d_ws, size_t ws_size,
                              hipStream_t stream) {
    float* out = (float*)d_out;
    float* ws = (float*)d_ws;

    const int want[9] = {1179648, 393216, 393216, 589824, 589824, 768, 49152, 512, 512};
    int role2in[9], used[9] = {0};
    bool ok = (n_in == 9);
    if (ok) {
        for (int r = 0; r < 9; ++r) {
            int found = -1;
            for (int i = 0; i < 9 && found < 0; ++i)
                if (!used[i] && in_sizes[i] == want[r]) found = i;
            if (found < 0) { ok = false; break; }
            used[found] = 1;
            role2in[r] = found;
        }
    }
    if (!ok) for (int r = 0; r < 9; ++r) role2in[r] = r;

    const void* x    = d_in[role2in[0]];
    const void* Wq   = d_in[role2in[1]];
    const void* Wk   = d_in[role2in[2]];
    const void* Wv   = d_in[role2in[3]];
    const void* Wout = d_in[role2in[4]];
    const void* bout = d_in[role2in[5]];
    const void* Wpos = d_in[role2in[6]];
    const void* rcb  = d_in[role2in[7]];
    const void* rpb  = d_in[role2in[8]];

    // One-time host-side occupancy probe (no stream ops; capture-safe, R1-proven).
    static int inited = 0;
    static int nCU = 256, occB = 0;
    if (!inited) {
        hipDeviceProp_t prop;
        int dev = 0;
        (void)hipGetDevice(&dev);
        if (hipGetDeviceProperties(&prop, dev) == hipSuccess && prop.multiProcessorCount > 0)
            nCU = prop.multiProcessorCount;
        if (hipOccupancyMaxActiveBlocksPerMultiprocessor(&occB, fused_ao, 512, 0) != hipSuccess)
            occB = 0;
        inited = 1;
    }

    hipLaunchKernelGGL(prep, dim3(1115), dim3(256), 0, stream,
                       x, Wq, Wk, Wv, Wout, Wpos, ws);
    hipLaunchKernelGGL(qkv_reg, dim3(24, 28), dim3(256), 0, stream,
                       rcb, rpb, ws);

    bool doneB = false;
    if (occB > 0) {
        int gridB = occB * nCU; if (gridB > 768) gridB = 768;
        void* argsB[] = {(void*)&bout, (void*)&ws, (void*)&out};
        doneB = hipLaunchCooperativeKernel(fused_ao, dim3(gridB), dim3(512),
                                           argsB, 0, stream) == hipSuccess;
    }
    if (!doneB) {
        hipLaunchKernelGGL(attn_mfma, dim3(768), dim3(512), 0, stream, ws);
        hipLaunchKernelGGL(out_reg, dim3(24, 12), dim3(256), 0, stream,
                           bout, ws, out);
    }
}

// Round 6
// 147.587 us; speedup vs baseline: 1.7450x; 1.7450x over previous
//
#include <hip/hip_runtime.h>
#include <stdint.h>

#define NTOK 1536
#define CDIM 768
#define NH 8
#define DKH 64
#define DVH 96
#define NF 96

typedef unsigned short u16;
typedef __attribute__((ext_vector_type(8))) short s16x8;   // 8 bf16 (4 VGPRs)
typedef __attribute__((ext_vector_type(4))) float f32x4;   // MFMA acc

__device__ __forceinline__ float b2f(u16 u) {
    union { uint32_t i; float f; } v; v.i = ((uint32_t)u) << 16; return v.f;
}
__device__ __forceinline__ u16 f2b(float f) {
    union { float f; uint32_t i; } v; v.f = f;
    uint32_t x = v.i;
    return (u16)((x + 0x7FFFu + ((x >> 16) & 1u)) >> 16);
}
__device__ __forceinline__ float ldin(const void* p, int i, int f32) {
    return f32 ? ((const float*)p)[i] : b2f(((const u16*)p)[i]);
}

// Inline wave-uniform dtype probe: scans first 256 u16 words.  A true-bf16
// buffer never decodes |v|>=1e6; fp32 mantissa-low words do w.p. ~0.42 each
// (~128 of the 256 samples) -> miss prob ~3e-29.  Returns 1 iff fp32.
__device__ __forceinline__ int probe_f32(const void* p) {
    const u16* a = (const u16*)p;
    int lane = threadIdx.x & 63;
    int bad = 0;
#pragma unroll
    for (int t = 0; t < 4; ++t) {
        float v = b2f(a[lane + t * 64]);
        if (!(fabsf(v) < 1e6f)) bad = 1;
    }
    return __ballot(bad) != 0ull;
}

// Fragment-major: element (m, kk) of a (16 x 32k) 512-elem block sits at
// ((kk>>3)*16 + m)*8 + (kk&7)  == lane*8 + slot.
#define FIDX(m, kk) ((((kk) >> 3) * 16 + (m)) * 8 + ((kk) & 7))

// ---------------------------------------------------------------------------
// ws layout (float offsets). ~14.8 MB.
// ---------------------------------------------------------------------------
#define OFF_WSUF 16
#define OFF_S11  (OFF_WSUF + 5632)
#define OFF_QF   (OFF_S11 + 147456)     // u16: qfrag  (h,ti:96,kc2:2)  A-frags
#define OFF_KF   (OFF_QF + 393216)      // u16: kfrag  (h,tj:96,kc2:2)  B-frags
#define OFF_VF   (OFF_KF + 393216)      // u16: vfrag  (h,jc:48,nt:6)   B-frags
#define OFF_AOF  (OFF_VF + 589824)      // u16: aofrag (ti:96,kc:24)    A-frags
#define OFF_XF   (OFF_AOF + 589824)     // u16: xfrag  (ti:96,kc:24)    A-frags
#define OFF_WF   (OFF_XF + 589824)      // u16: wfrag  (tn:112,kc:24)   B-frags
#define OFF_WOF  (OFF_WF + 688128)      // u16: wofrag (tn:48,kc:24)    B-frags

// ---------------------------------------------------------------------------
// Kernel PR: build fragment buffers.  NO LDS, NO barriers, high MLP.
// (R0-proven version, verbatim.)
// ---------------------------------------------------------------------------
__global__ __launch_bounds__(256) void prep(const void* __restrict__ x,
                                            const void* __restrict__ Wq,
                                            const void* __restrict__ Wk,
                                            const void* __restrict__ Wv,
                                            const void* __restrict__ Wout,
                                            const void* __restrict__ Wpos,
                                            float* __restrict__ ws) {
    int bx = blockIdx.x, tid = threadIdx.x;
    int wv = tid >> 6, L = tid & 63;

    if (bx < 144) {
        int f = probe_f32(x);
        u16* dst = (u16*)(ws + OFF_XF);
        int cbase = (bx * 4 + wv) * 4;
        int m = L & 15, kq = L >> 4;
        int srcs[4];
#pragma unroll
        for (int c = 0; c < 4; ++c) {
            int ch = cbase + c;
            int ti = ch / 24, kc = ch % 24;
            srcs[c] = (ti * 16 + m) * CDIM + kc * 32 + kq * 8;
        }
        if (f) {
            float4 a[4][2];
#pragma unroll
            for (int c = 0; c < 4; ++c) {
                const float* xp = (const float*)x + srcs[c];
                a[c][0] = *(const float4*)(xp);
                a[c][1] = *(const float4*)(xp + 4);
            }
#pragma unroll
            for (int c = 0; c < 4; ++c) {
                union { u16 u[8]; uint4 v; } pk;
                pk.u[0] = f2b(a[c][0].x); pk.u[1] = f2b(a[c][0].y);
                pk.u[2] = f2b(a[c][0].z); pk.u[3] = f2b(a[c][0].w);
                pk.u[4] = f2b(a[c][1].x); pk.u[5] = f2b(a[c][1].y);
                pk.u[6] = f2b(a[c][1].z); pk.u[7] = f2b(a[c][1].w);
                *(uint4*)(dst + (cbase + c) * 512 + L * 8) = pk.v;
            }
        } else {
            uint4 v[4];
#pragma unroll
            for (int c = 0; c < 4; ++c) v[c] = *(const uint4*)((const u16*)x + srcs[c]);
#pragma unroll
            for (int c = 0; c < 4; ++c)
                *(uint4*)(dst + (cbase + c) * 512 + L * 8) = v[c];
        }
        return;
    }
    if (bx < 1104) {
        int c = (bx - 144) * 4 + wv;
        const void* src; int ld, cn0; u16* dst; int kc;
        if (c < 2688) {
            int tn = c / 24; kc = c % 24;
            int n0 = tn * 16;
            dst = (u16*)(ws + OFF_WF) + c * 512;
            if (n0 < 512)       { src = Wq; ld = 512;  cn0 = n0; }
            else if (n0 < 1024) { src = Wk; ld = 512;  cn0 = n0 - 512; }
            else                { src = Wv; ld = CDIM; cn0 = n0 - 1024; }
        } else {
            int c2 = c - 2688;
            int tn = c2 / 24; kc = c2 % 24;
            dst = (u16*)(ws + OFF_WOF) + c2 * 512;
            src = Wout; ld = CDIM; cn0 = tn * 16;
        }
        int f = probe_f32(src);
        int nn = L & 15, kq = L >> 4;
        int base = (kc * 32 + kq * 8) * ld + cn0 + nn;
        union { u16 u[8]; uint4 v; } pk;
        if (f) {
            const float* sp = (const float*)src + base;
            float a0 = sp[0], a1 = sp[ld], a2 = sp[2 * ld], a3 = sp[3 * ld];
            float a4 = sp[4 * ld], a5 = sp[5 * ld], a6 = sp[6 * ld], a7 = sp[7 * ld];
            pk.u[0] = f2b(a0); pk.u[1] = f2b(a1); pk.u[2] = f2b(a2); pk.u[3] = f2b(a3);
            pk.u[4] = f2b(a4); pk.u[5] = f2b(a5); pk.u[6] = f2b(a6); pk.u[7] = f2b(a7);
        } else {
            const u16* sp = (const u16*)src + base;
            pk.u[0] = sp[0]; pk.u[1] = sp[ld]; pk.u[2] = sp[2 * ld]; pk.u[3] = sp[3 * ld];
            pk.u[4] = sp[4 * ld]; pk.u[5] = sp[5 * ld]; pk.u[6] = sp[6 * ld]; pk.u[7] = sp[7 * ld];
        }
        *(uint4*)(dst + L * 8) = pk.v;
        return;
    }
    // ---- wsuf ----
    int t = bx - 1104;
    int f = probe_f32(Wpos);
    for (int hd = tid; hd < 512; hd += 256) {
        float s0 = 0.f, s1 = 0.f, s2 = 0.f, s3 = 0.f;
        int f0 = t;
        for (; f0 + 4 <= NF; f0 += 4) {
            s0 += ldin(Wpos, f0 * 512 + hd, f);
            s1 += ldin(Wpos, (f0 + 1) * 512 + hd, f);
            s2 += ldin(Wpos, (f0 + 2) * 512 + hd, f);
            s3 += ldin(Wpos, (f0 + 3) * 512 + hd, f);
        }
        for (; f0 < NF; ++f0) s0 += ldin(Wpos, f0 * 512 + hd, f);
        ws[OFF_WSUF + t * 512 + hd] = (s0 + s1) + (s2 + s3);
    }
}

// ---------------------------------------------------------------------------
// Kernel 1: QKV GEMM, register-direct MFMA (R0-proven version, verbatim).
// ---------------------------------------------------------------------------
__global__ __launch_bounds__(256) void qkv_reg(const void* __restrict__ rcb,
                                               const void* __restrict__ rpb,
                                               float* __restrict__ ws) {
    __shared__ float qt[64 * 68];
    __shared__ float rpd[12];
    const u16* xf = (const u16*)(ws + OFF_XF);
    const u16* wf = (const u16*)(ws + OFF_WF);
    u16* qf = (u16*)(ws + OFF_QF);
    u16* kf = (u16*)(ws + OFF_KF);
    u16* vf = (u16*)(ws + OFF_VF);

    int tid = threadIdx.x;
    int lane = tid & 63, w = tid >> 6;
    int quad = lane >> 4, col = lane & 15;
    int ti4 = blockIdx.x;
    int tn4 = blockIdx.y;
    int tn = tn4 * 4 + w;
    int i0 = ti4 * 64;
    bool isQ = (tn4 < 8);
    int hq = tn4;

    s16x8 bw0, bw1;
    int f32p = 0, f32c = 0;
    if (isQ) {
        f32p = probe_f32(rpb);
        f32c = probe_f32(rcb);
        int t = lane & 15, kq = lane >> 4;
        union { u16 u[8]; s16x8 v; } p0, p1;
#pragma unroll
        for (int j = 0; j < 8; ++j) {
            float v0 = 0.f, v1 = 0.f;
            if (t < 11) {
                v0 = ws[OFF_WSUF + t * 512 + hq * 64 + kq * 8 + j];
                v1 = ws[OFF_WSUF + t * 512 + hq * 64 + 32 + kq * 8 + j];
            }
            p0.u[j] = f2b(v0); p1.u[j] = f2b(v1);
        }
        bw0 = p0.v; bw1 = p1.v;
        if (tid < 12) {
            float s = 0.f;
            if (tid < 11) {
                const float* wp = ws + OFF_WSUF + tid * 512 + hq * 64;
                for (int d = 0; d < 64; ++d) s += ldin(rpb, hq * 64 + d, f32p) * wp[d];
            }
            rpd[tid] = s;
        }
    }

    f32x4 acc[4];
#pragma unroll
    for (int mt = 0; mt < 4; ++mt) acc[mt] = (f32x4){0.f, 0.f, 0.f, 0.f};

    const u16* bp = wf + (tn * 24) * 512 + lane * 8;
    const u16* ap = xf + (ti4 * 4 * 24) * 512 + lane * 8;
#pragma unroll 4
    for (int kc = 0; kc < 24; ++kc) {
        s16x8 bfrag = *(const s16x8*)(bp + kc * 512);
#pragma unroll
        for (int mt = 0; mt < 4; ++mt) {
            s16x8 afrag = *(const s16x8*)(ap + (mt * 24 + kc) * 512);
            acc[mt] = __builtin_amdgcn_mfma_f32_16x16x32_bf16(afrag, bfrag, acc[mt], 0, 0, 0);
        }
    }

    if (isQ) {
#pragma unroll
        for (int mt = 0; mt < 4; ++mt)
#pragma unroll
            for (int r = 0; r < 4; ++r)
                qt[(mt * 16 + quad * 4 + r) * 68 + w * 16 + col] = acc[mt][r] * 0.125f;
        __syncthreads();
        int m = lane & 15, kq = lane >> 4;
#pragma unroll
        for (int kc2 = 0; kc2 < 2; ++kc2) {
            union { u16 u[8]; uint4 v; } pk;
#pragma unroll
            for (int j = 0; j < 8; ++j) {
                int d = kc2 * 32 + kq * 8 + j;
                pk.u[j] = f2b(qt[(w * 16 + m) * 68 + d] + ldin(rcb, hq * 64 + d, f32c));
            }
            *(uint4*)(qf + (((hq * 96 + ti4 * 4 + w) * 2 + kc2) * 512) + lane * 8) = pk.v;
        }
        union { u16 u[8]; s16x8 v; } qa0, qa1;
#pragma unroll
        for (int j = 0; j < 8; ++j) {
            qa0.u[j] = f2b(qt[(w * 16 + m) * 68 + kq * 8 + j]);
            qa1.u[j] = f2b(qt[(w * 16 + m) * 68 + 32 + kq * 8 + j]);
        }
        f32x4 s11a = (f32x4){0.f, 0.f, 0.f, 0.f};
        s11a = __builtin_amdgcn_mfma_f32_16x16x32_bf16(qa0.v, bw0, s11a, 0, 0, 0);
        s11a = __builtin_amdgcn_mfma_f32_16x16x32_bf16(qa1.v, bw1, s11a, 0, 0, 0);
        if (col < 12) {
            float rp = rpd[col];
            float* s11 = ws + OFF_S11;
#pragma unroll
            for (int r = 0; r < 4; ++r)
                s11[(hq * NTOK + i0 + w * 16 + quad * 4 + r) * 12 + col] = s11a[r] + rp;
        }
    } else if (tn < 64) {
        int h = (tn >> 2) - 8;
        int d = ((tn & 3) * 16) + col;
#pragma unroll
        for (int mt = 0; mt < 4; ++mt) {
            int tj = ti4 * 4 + mt;
#pragma unroll
            for (int r = 0; r < 4; ++r) {
                int nn = quad * 4 + r;
                kf[((h * 96 + tj) * 2 + (d >> 5)) * 512 + FIDX(nn, d & 31)] = f2b(acc[mt][r]);
            }
        }
    } else {
        int c = tn * 16 + col - 1024;
        int h = c / 96, d = c % 96;
        int nt = d >> 4, nn = d & 15;
#pragma unroll
        for (int mt = 0; mt < 4; ++mt) {
#pragma unroll
            for (int r = 0; r < 4; ++r) {
                int j = i0 + mt * 16 + quad * 4 + r;
                int jc = j >> 5, kk = j & 31;
                vf[((h * 48 + jc) * 6 + nt) * 512 + FIDX(nn, kk)] = f2b(acc[mt][r]);
            }
        }
    }
}

// ---------------------------------------------------------------------------
// Kernel 3: MFMA flash attention.  ONE change vs the R0 147us version:
// pbuf (chunk-loop-only) and Om (epilogue-only) share LDS via a union,
// cutting LDS 59.6KB -> 50.4KB => 3 blocks/CU (24 waves/CU), so all 768
// blocks fit one scheduling round.  Requires one extra __syncthreads
// between the last PV (pbuf read) and the Om store (aliasing).
// ---------------------------------------------------------------------------
__global__ __launch_bounds__(512) void attn_mfma(float* __restrict__ ws) {
    __shared__ float s11b[192];
    __shared__ float lw[8][16];
    __shared__ union {
        alignas(16) u16 pbuf[8][16 * 36];
        float Om[8][16 * 96];
    } sh;

    const u16* qf = (const u16*)(ws + OFF_QF);
    const u16* kf = (const u16*)(ws + OFF_KF);
    const u16* vf = (const u16*)(ws + OFF_VF);
    const float* s11 = ws + OFF_S11;
    u16* aof = (u16*)(ws + OFF_AOF);

    int h = blockIdx.x & 7;               // XCD-affine
    int ti = blockIdx.x >> 3;
    int i0 = ti * 16;
    int tid = threadIdx.x;
    int wv = tid >> 6, lane = tid & 63;
    int quad = lane >> 4, col = lane & 15;

    if (tid < 192) s11b[tid] = s11[(h * NTOK + i0 + tid / 12) * 12 + tid % 12];
    const u16* qp = qf + ((h * 96 + ti) * 2) * 512 + lane * 8;
    s16x8 a_lo = *(const s16x8*)(qp);
    s16x8 a_hi = *(const s16x8*)(qp + 512);
    __syncthreads();

    f32x4 O[6];
    float lsum[4];
#pragma unroll
    for (int nt = 0; nt < 6; ++nt) O[nt] = (f32x4){0.f, 0.f, 0.f, 0.f};
#pragma unroll
    for (int r = 0; r < 4; ++r) lsum[r] = 0.f;

    // prefetch chunk 0 K-frags
    const u16* kbase = kf + ((h * 96 + wv * 12) * 2) * 512 + lane * 8;
    s16x8 k0lo = *(const s16x8*)(kbase);
    s16x8 k0hi = *(const s16x8*)(kbase + 512);
    s16x8 k1lo = *(const s16x8*)(kbase + 1024);
    s16x8 k1hi = *(const s16x8*)(kbase + 1536);

    for (int c = 0; c < 6; ++c) {
        // ---- QK^T with current K regs ----
        f32x4 t0 = (f32x4){0.f, 0.f, 0.f, 0.f};
        f32x4 t1 = (f32x4){0.f, 0.f, 0.f, 0.f};
        t0 = __builtin_amdgcn_mfma_f32_16x16x32_bf16(a_lo, k0lo, t0, 0, 0, 0);
        t0 = __builtin_amdgcn_mfma_f32_16x16x32_bf16(a_hi, k0hi, t0, 0, 0, 0);
        t1 = __builtin_amdgcn_mfma_f32_16x16x32_bf16(a_lo, k1lo, t1, 0, 0, 0);
        t1 = __builtin_amdgcn_mfma_f32_16x16x32_bf16(a_hi, k1hi, t1, 0, 0, 0);
        // ---- prefetch next chunk's K frags ----
        if (c < 5) {
            const u16* kn = kbase + (c + 1) * 2048;
            k0lo = *(const s16x8*)(kn);
            k0hi = *(const s16x8*)(kn + 512);
            k1lo = *(const s16x8*)(kn + 1024);
            k1hi = *(const s16x8*)(kn + 1536);
        }
        // ---- bias + exp(s-12) + store P ----
        int j0 = wv * 192 + c * 32;
        int lo1 = j0 - (i0 + 15), lo2 = i0 - (j0 + 31);
        int dmin = lo1 > 0 ? lo1 : (lo2 > 0 ? lo2 : 0);
        int dm1 = i0 + 15 - j0, dm2 = j0 + 31 - i0;
        int dmax = dm1 > dm2 ? dm1 : dm2;
        int tlo = 31 - __builtin_clz(dmin + 1);
        int thi = 31 - __builtin_clz(dmax + 1);
        if (tlo == thi) {
#pragma unroll
            for (int r = 0; r < 4; ++r) {
                int row = quad * 4 + r;
                float bv = s11b[row * 12 + tlo] - 12.f;
                float p0 = __expf(t0[r] + bv);
                float p1 = __expf(t1[r] + bv);
                sh.pbuf[wv][row * 36 + col] = f2b(p0);
                sh.pbuf[wv][row * 36 + 16 + col] = f2b(p1);
                lsum[r] += p0 + p1;
            }
        } else {
#pragma unroll
            for (int r = 0; r < 4; ++r) {
                int row = quad * 4 + r;
                int ig = i0 + row;
                int d0 = ig - (j0 + col); d0 = d0 < 0 ? -d0 : d0;
                int d1 = ig - (j0 + 16 + col); d1 = d1 < 0 ? -d1 : d1;
                float v0 = t0[r] + s11b[row * 12 + (31 - __builtin_clz(d0 + 1))];
                float v1 = t1[r] + s11b[row * 12 + (31 - __builtin_clz(d1 + 1))];
                float p0 = __expf(v0 - 12.f);
                float p1 = __expf(v1 - 12.f);
                sh.pbuf[wv][row * 36 + col] = f2b(p0);
                sh.pbuf[wv][row * 36 + 16 + col] = f2b(p1);
                lsum[r] += p0 + p1;
            }
        }
        // ---- PV (compiler inserts lgkmcnt for the pbuf RAW) ----
        int jc = wv * 6 + c;
        const u16* pr = &sh.pbuf[wv][col * 36 + quad * 8];
        union { s16x8 v; uint2 u2[2]; } pa;
        pa.u2[0] = *(const uint2*)(pr);
        pa.u2[1] = *(const uint2*)(pr + 4);
        const u16* vp = vf + ((h * 48 + jc) * 6) * 512 + lane * 8;
#pragma unroll
        for (int nt = 0; nt < 6; ++nt) {
            s16x8 vfr = *(const s16x8*)(vp + nt * 512);
            O[nt] = __builtin_amdgcn_mfma_f32_16x16x32_bf16(pa.v, vfr, O[nt], 0, 0, 0);
        }
    }

#pragma unroll
    for (int off = 1; off < 16; off <<= 1)
#pragma unroll
        for (int r = 0; r < 4; ++r) lsum[r] += __shfl_xor(lsum[r], off);
    if (col == 0)
#pragma unroll
        for (int r = 0; r < 4; ++r) lw[wv][quad * 4 + r] = lsum[r];
    __syncthreads();   // all waves done with pbuf before Om overwrites it
#pragma unroll
    for (int r = 0; r < 4; ++r) {
        int row = quad * 4 + r;
#pragma unroll
        for (int nt = 0; nt < 6; ++nt)
            sh.Om[wv][row * 96 + nt * 16 + col] = O[nt][r];
    }
    __syncthreads();
    for (int idx = tid; idx < 16 * 96; idx += 512) {
        int row = idx / 96, cc = idx % 96;
        float L = 0.f, val = 0.f;
#pragma unroll
        for (int v = 0; v < 8; ++v) { L += lw[v][row]; val += sh.Om[v][idx]; }
        aof[(ti * 24 + h * 3 + (cc >> 5)) * 512 + FIDX(row, cc & 31)] = f2b(val / L);
    }
}

// ---------------------------------------------------------------------------
// Kernel 4: output GEMM, register-direct MFMA (R0-proven version, verbatim).
// ---------------------------------------------------------------------------
__global__ __launch_bounds__(256) void out_reg(const void* __restrict__ bout,
                                               float* __restrict__ ws,
                                               float* __restrict__ out) {
    const u16* af = (const u16*)(ws + OFF_AOF);
    const u16* wof = (const u16*)(ws + OFF_WOF);
    int f32b = probe_f32(bout);

    int tid = threadIdx.x;
    int lane = tid & 63, w = tid >> 6;
    int quad = lane >> 4, col = lane & 15;
    int ti4 = blockIdx.x;
    int tn = blockIdx.y * 4 + w;
    int i0 = ti4 * 64;
    int n0 = blockIdx.y * 64;

    f32x4 acc[4];
#pragma unroll
    for (int mt = 0; mt < 4; ++mt) acc[mt] = (f32x4){0.f, 0.f, 0.f, 0.f};

    const u16* bp = wof + (tn * 24) * 512 + lane * 8;
    const u16* ap = af + (ti4 * 4 * 24) * 512 + lane * 8;
#pragma unroll 4
    for (int kc = 0; kc < 24; ++kc) {
        s16x8 bfrag = *(const s16x8*)(bp + kc * 512);
#pragma unroll
        for (int mt = 0; mt < 4; ++mt) {
            s16x8 afrag = *(const s16x8*)(ap + (mt * 24 + kc) * 512);
            acc[mt] = __builtin_amdgcn_mfma_f32_16x16x32_bf16(afrag, bfrag, acc[mt], 0, 0, 0);
        }
    }

    int c = n0 + w * 16 + col;
    float bias = ldin(bout, c, f32b);
#pragma unroll
    for (int mt = 0; mt < 4; ++mt) {
#pragma unroll
        for (int r = 0; r < 4; ++r) {
            int i = i0 + mt * 16 + quad * 4 + r;
            out[i * CDIM + c] = acc[mt][r] + bias;
        }
    }
}

// ---------------------------------------------------------------------------
extern "C" void kernel_launch(void* const* d_in, const int* in_sizes, int n_in,
                              void* d_out, int out_size, void* d_ws, size_t ws_size,
                              hipStream_t stream) {
    float* out = (float*)d_out;
    float* ws = (float*)d_ws;

    const int want[9] = {1179648, 393216, 393216, 589824, 589824, 768, 49152, 512, 512};
    int role2in[9], used[9] = {0};
    bool ok = (n_in == 9);
    if (ok) {
        for (int r = 0; r < 9; ++r) {
            int found = -1;
            for (int i = 0; i < 9 && found < 0; ++i)
                if (!used[i] && in_sizes[i] == want[r]) found = i;
            if (found < 0) { ok = false; break; }
            used[found] = 1;
            role2in[r] = found;
        }
    }
    if (!ok) for (int r = 0; r < 9; ++r) role2in[r] = r;

    const void* x    = d_in[role2in[0]];
    const void* Wq   = d_in[role2in[1]];
    const void* Wk   = d_in[role2in[2]];
    const void* Wv   = d_in[role2in[3]];
    const void* Wout = d_in[role2in[4]];
    const void* bout = d_in[role2in[5]];
    const void* Wpos = d_in[role2in[6]];
    const void* rcb  = d_in[role2in[7]];
    const void* rpb  = d_in[role2in[8]];

    hipLaunchKernelGGL(prep, dim3(1115), dim3(256), 0, stream,
                       x, Wq, Wk, Wv, Wout, Wpos, ws);
    hipLaunchKernelGGL(qkv_reg, dim3(24, 28), dim3(256), 0, stream,
                       rcb, rpb, ws);
    hipLaunchKernelGGL(attn_mfma, dim3(768), dim3(512), 0, stream, ws);
    hipLaunchKernelGGL(out_reg, dim3(24, 12), dim3(256), 0, stream,
                       bout, ws, out);
}

// Round 8
// 147.205 us; speedup vs baseline: 1.7495x; 1.0026x over previous
//
#include <hip/hip_runtime.h>
#include <stdint.h>

#define NTOK 1536
#define CDIM 768
#define NH 8
#define DKH 64
#define DVH 96
#define NF 96

typedef unsigned short u16;
typedef __attribute__((ext_vector_type(8))) short s16x8;   // 8 bf16 (4 VGPRs)
typedef __attribute__((ext_vector_type(4))) float f32x4;   // MFMA acc

__device__ __forceinline__ float b2f(u16 u) {
    union { uint32_t i; float f; } v; v.i = ((uint32_t)u) << 16; return v.f;
}
__device__ __forceinline__ u16 f2b(float f) {
    union { float f; uint32_t i; } v; v.f = f;
    uint32_t x = v.i;
    return (u16)((x + 0x7FFFu + ((x >> 16) & 1u)) >> 16);
}
__device__ __forceinline__ float ldin(const void* p, int i, int f32) {
    return f32 ? ((const float*)p)[i] : b2f(((const u16*)p)[i]);
}

// Inline wave-uniform dtype probe (see earlier rounds).
__device__ __forceinline__ int probe_f32(const void* p) {
    const u16* a = (const u16*)p;
    int lane = threadIdx.x & 63;
    int bad = 0;
#pragma unroll
    for (int t = 0; t < 4; ++t) {
        float v = b2f(a[lane + t * 64]);
        if (!(fabsf(v) < 1e6f)) bad = 1;
    }
    return __ballot(bad) != 0ull;
}

#define FIDX(m, kk) ((((kk) >> 3) * 16 + (m)) * 8 + ((kk) & 7))

// ---------------------------------------------------------------------------
// ws layout (float offsets).  First 4 KB reserved for barrier counters
// (zeroed by hipMemsetAsync each launch): K1 slots at int[0..255],
// K2 slots at int[256..511] (8 slots x 128B stride each).
// ---------------------------------------------------------------------------
#define OFF_WSUF 1024
#define OFF_S11  (OFF_WSUF + 5632)
#define OFF_QF   (OFF_S11 + 147456)
#define OFF_KF   (OFF_QF + 393216)
#define OFF_VF   (OFF_KF + 393216)
#define OFF_AOF  (OFF_VF + 589824)
#define OFF_XF   (OFF_AOF + 589824)
#define OFF_WF   (OFF_XF + 589824)
#define OFF_WOF  (OFF_WF + 688128)

// ---------------------------------------------------------------------------
// Lean sharded grid barrier.  Co-residency is guaranteed by launching the
// grid COOPERATIVELY (runtime-certified, as in R1/R5 which completed on this
// harness) with grid <= occ*nCU; so the spin cannot deadlock.  8 counter
// cachelines avoid the single-line cross-XCD RMW serialization that makes
// cg::this_grid().sync() cost 100+ us at this block count.  Spin is capped:
// worst case self-releases (~seconds) -> wrong answer, never a GPU hang.
// ---------------------------------------------------------------------------
__device__ __forceinline__ void gbar_arrive(int* cbase, int bid) {
    __threadfence();                    // release phase-1 ws writes
    __syncthreads();
    if (threadIdx.x == 0)
        __hip_atomic_fetch_add(&cbase[(bid & 7) * 32], 1,
                               __ATOMIC_RELEASE, __HIP_MEMORY_SCOPE_AGENT);
}
__device__ __forceinline__ void gbar_wait(int* cbase, int expected) {
    if (threadIdx.x == 0) {
        long spins = 0;
        int total;
        do {
            total = 0;
#pragma unroll
            for (int s = 0; s < 8; ++s)
                total += __hip_atomic_load(&cbase[s * 32],
                                           __ATOMIC_ACQUIRE, __HIP_MEMORY_SCOPE_AGENT);
            if (total < expected) __builtin_amdgcn_s_sleep(32);
        } while (total < expected && ++spins < (1L << 22));
    }
    __syncthreads();
    __threadfence();                    // acquire before phase-2 reads
}

// ===========================================================================
// Fallback kernels (R6 state, harness-verified at 147.6us).
// ===========================================================================
__global__ __launch_bounds__(256) void prep(const void* __restrict__ x,
                                            const void* __restrict__ Wq,
                                            const void* __restrict__ Wk,
                                            const void* __restrict__ Wv,
                                            const void* __restrict__ Wout,
                                            const void* __restrict__ Wpos,
                                            float* __restrict__ ws) {
    int bx = blockIdx.x, tid = threadIdx.x;
    int wv = tid >> 6, L = tid & 63;

    if (bx < 144) {
        int f = probe_f32(x);
        u16* dst = (u16*)(ws + OFF_XF);
        int cbase = (bx * 4 + wv) * 4;
        int m = L & 15, kq = L >> 4;
        int srcs[4];
#pragma unroll
        for (int c = 0; c < 4; ++c) {
            int ch = cbase + c;
            int ti = ch / 24, kc = ch % 24;
            srcs[c] = (ti * 16 + m) * CDIM + kc * 32 + kq * 8;
        }
        if (f) {
            float4 a[4][2];
#pragma unroll
            for (int c = 0; c < 4; ++c) {
                const float* xp = (const float*)x + srcs[c];
                a[c][0] = *(const float4*)(xp);
                a[c][1] = *(const float4*)(xp + 4);
            }
#pragma unroll
            for (int c = 0; c < 4; ++c) {
                union { u16 u[8]; uint4 v; } pk;
                pk.u[0] = f2b(a[c][0].x); pk.u[1] = f2b(a[c][0].y);
                pk.u[2] = f2b(a[c][0].z); pk.u[3] = f2b(a[c][0].w);
                pk.u[4] = f2b(a[c][1].x); pk.u[5] = f2b(a[c][1].y);
                pk.u[6] = f2b(a[c][1].z); pk.u[7] = f2b(a[c][1].w);
                *(uint4*)(dst + (cbase + c) * 512 + L * 8) = pk.v;
            }
        } else {
            uint4 v[4];
#pragma unroll
            for (int c = 0; c < 4; ++c) v[c] = *(const uint4*)((const u16*)x + srcs[c]);
#pragma unroll
            for (int c = 0; c < 4; ++c)
                *(uint4*)(dst + (cbase + c) * 512 + L * 8) = v[c];
        }
        return;
    }
    if (bx < 1104) {
        int c = (bx - 144) * 4 + wv;
        const void* src; int ld, cn0; u16* dst; int kc;
        if (c < 2688) {
            int tn = c / 24; kc = c % 24;
            int n0 = tn * 16;
            dst = (u16*)(ws + OFF_WF) + c * 512;
            if (n0 < 512)       { src = Wq; ld = 512;  cn0 = n0; }
            else if (n0 < 1024) { src = Wk; ld = 512;  cn0 = n0 - 512; }
            else                { src = Wv; ld = CDIM; cn0 = n0 - 1024; }
        } else {
            int c2 = c - 2688;
            int tn = c2 / 24; kc = c2 % 24;
            dst = (u16*)(ws + OFF_WOF) + c2 * 512;
            src = Wout; ld = CDIM; cn0 = tn * 16;
        }
        int f = probe_f32(src);
        int nn = L & 15, kq = L >> 4;
        int base = (kc * 32 + kq * 8) * ld + cn0 + nn;
        union { u16 u[8]; uint4 v; } pk;
        if (f) {
            const float* sp = (const float*)src + base;
            float a0 = sp[0], a1 = sp[ld], a2 = sp[2 * ld], a3 = sp[3 * ld];
            float a4 = sp[4 * ld], a5 = sp[5 * ld], a6 = sp[6 * ld], a7 = sp[7 * ld];
            pk.u[0] = f2b(a0); pk.u[1] = f2b(a1); pk.u[2] = f2b(a2); pk.u[3] = f2b(a3);
            pk.u[4] = f2b(a4); pk.u[5] = f2b(a5); pk.u[6] = f2b(a6); pk.u[7] = f2b(a7);
        } else {
            const u16* sp = (const u16*)src + base;
            pk.u[0] = sp[0]; pk.u[1] = sp[ld]; pk.u[2] = sp[2 * ld]; pk.u[3] = sp[3 * ld];
            pk.u[4] = sp[4 * ld]; pk.u[5] = sp[5 * ld]; pk.u[6] = sp[6 * ld]; pk.u[7] = sp[7 * ld];
        }
        *(uint4*)(dst + L * 8) = pk.v;
        return;
    }
    int t = bx - 1104;
    int f = probe_f32(Wpos);
    for (int hd = tid; hd < 512; hd += 256) {
        float s0 = 0.f, s1 = 0.f, s2 = 0.f, s3 = 0.f;
        int f0 = t;
        for (; f0 + 4 <= NF; f0 += 4) {
            s0 += ldin(Wpos, f0 * 512 + hd, f);
            s1 += ldin(Wpos, (f0 + 1) * 512 + hd, f);
            s2 += ldin(Wpos, (f0 + 2) * 512 + hd, f);
            s3 += ldin(Wpos, (f0 + 3) * 512 + hd, f);
        }
        for (; f0 < NF; ++f0) s0 += ldin(Wpos, f0 * 512 + hd, f);
        ws[OFF_WSUF + t * 512 + hd] = (s0 + s1) + (s2 + s3);
    }
}

// -------- prep phase body for fused K1 (one unit) --------------------------
__device__ __forceinline__ void prep_unit(int u, const void* x, const void* Wq,
                                          const void* Wk, const void* Wv,
                                          const void* Wout, const void* Wpos,
                                          float* ws) {
    int tid = threadIdx.x;
    int wv = tid >> 6, L = tid & 63;
    if (u < 144) {
        int f = probe_f32(x);
        u16* dst = (u16*)(ws + OFF_XF);
        int cbase = (u * 4 + wv) * 4;
        int m = L & 15, kq = L >> 4;
        int srcs[4];
#pragma unroll
        for (int c = 0; c < 4; ++c) {
            int ch = cbase + c;
            int ti = ch / 24, kc = ch % 24;
            srcs[c] = (ti * 16 + m) * CDIM + kc * 32 + kq * 8;
        }
        if (f) {
            float4 a[4][2];
#pragma unroll
            for (int c = 0; c < 4; ++c) {
                const float* xp = (const float*)x + srcs[c];
                a[c][0] = *(const float4*)(xp);
                a[c][1] = *(const float4*)(xp + 4);
            }
#pragma unroll
            for (int c = 0; c < 4; ++c) {
                union { u16 uu[8]; uint4 v; } pk;
                pk.uu[0] = f2b(a[c][0].x); pk.uu[1] = f2b(a[c][0].y);
                pk.uu[2] = f2b(a[c][0].z); pk.uu[3] = f2b(a[c][0].w);
                pk.uu[4] = f2b(a[c][1].x); pk.uu[5] = f2b(a[c][1].y);
                pk.uu[6] = f2b(a[c][1].z); pk.uu[7] = f2b(a[c][1].w);
                *(uint4*)(dst + (cbase + c) * 512 + L * 8) = pk.v;
            }
        } else {
            uint4 v[4];
#pragma unroll
            for (int c = 0; c < 4; ++c) v[c] = *(const uint4*)((const u16*)x + srcs[c]);
#pragma unroll
            for (int c = 0; c < 4; ++c)
                *(uint4*)(dst + (cbase + c) * 512 + L * 8) = v[c];
        }
    } else if (u < 1104) {
        int c = (u - 144) * 4 + wv;
        const void* src; int ld, cn0; u16* dst; int kc;
        if (c < 2688) {
            int tn = c / 24; kc = c % 24;
            int n0 = tn * 16;
            dst = (u16*)(ws + OFF_WF) + c * 512;
            if (n0 < 512)       { src = Wq; ld = 512;  cn0 = n0; }
            else if (n0 < 1024) { src = Wk; ld = 512;  cn0 = n0 - 512; }
            else                { src = Wv; ld = CDIM; cn0 = n0 - 1024; }
        } else {
            int c2 = c - 2688;
            int tn = c2 / 24; kc = c2 % 24;
            dst = (u16*)(ws + OFF_WOF) + c2 * 512;
            src = Wout; ld = CDIM; cn0 = tn * 16;
        }
        int f = probe_f32(src);
        int nn = L & 15, kq = L >> 4;
        int base = (kc * 32 + kq * 8) * ld + cn0 + nn;
        union { u16 uu[8]; uint4 v; } pk;
        if (f) {
            const float* sp = (const float*)src + base;
            float a0 = sp[0], a1 = sp[ld], a2 = sp[2 * ld], a3 = sp[3 * ld];
            float a4 = sp[4 * ld], a5 = sp[5 * ld], a6 = sp[6 * ld], a7 = sp[7 * ld];
            pk.uu[0] = f2b(a0); pk.uu[1] = f2b(a1); pk.uu[2] = f2b(a2); pk.uu[3] = f2b(a3);
            pk.uu[4] = f2b(a4); pk.uu[5] = f2b(a5); pk.uu[6] = f2b(a6); pk.uu[7] = f2b(a7);
        } else {
            const u16* sp = (const u16*)src + base;
            pk.uu[0] = sp[0]; pk.uu[1] = sp[ld]; pk.uu[2] = sp[2 * ld]; pk.uu[3] = sp[3 * ld];
            pk.uu[4] = sp[4 * ld]; pk.uu[5] = sp[5 * ld]; pk.uu[6] = sp[6 * ld]; pk.uu[7] = sp[7 * ld];
        }
        *(uint4*)(dst + L * 8) = pk.v;
    } else {
        int t = u - 1104;
        int f = probe_f32(Wpos);
        for (int hd = tid; hd < 512; hd += 256) {
            float s0 = 0.f, s1 = 0.f, s2 = 0.f, s3 = 0.f;
            int f0 = t;
            for (; f0 + 4 <= NF; f0 += 4) {
                s0 += ldin(Wpos, f0 * 512 + hd, f);
                s1 += ldin(Wpos, (f0 + 1) * 512 + hd, f);
                s2 += ldin(Wpos, (f0 + 2) * 512 + hd, f);
                s3 += ldin(Wpos, (f0 + 3) * 512 + hd, f);
            }
            for (; f0 < NF; ++f0) s0 += ldin(Wpos, f0 * 512 + hd, f);
            ws[OFF_WSUF + t * 512 + hd] = (s0 + s1) + (s2 + s3);
        }
    }
}

// -------- qkv phase body ---------------------------------------------------
__device__ __forceinline__ void qkv_body(int ti4, int tn4,
                                         const void* rcb, const void* rpb,
                                         float* ws, float* qt, float* rpd) {
    const u16* xf = (const u16*)(ws + OFF_XF);
    const u16* wf = (const u16*)(ws + OFF_WF);
    u16* qf = (u16*)(ws + OFF_QF);
    u16* kf = (u16*)(ws + OFF_KF);
    u16* vf = (u16*)(ws + OFF_VF);

    int tid = threadIdx.x;
    int lane = tid & 63, w = tid >> 6;
    int quad = lane >> 4, col = lane & 15;
    int tn = tn4 * 4 + w;
    int i0 = ti4 * 64;
    bool isQ = (tn4 < 8);
    int hq = tn4;

    s16x8 bw0, bw1;
    int f32p = 0, f32c = 0;
    if (isQ) {
        f32p = probe_f32(rpb);
        f32c = probe_f32(rcb);
        int t = lane & 15, kq = lane >> 4;
        union { u16 u[8]; s16x8 v; } p0, p1;
#pragma unroll
        for (int j = 0; j < 8; ++j) {
            float v0 = 0.f, v1 = 0.f;
            if (t < 11) {
                v0 = ws[OFF_WSUF + t * 512 + hq * 64 + kq * 8 + j];
                v1 = ws[OFF_WSUF + t * 512 + hq * 64 + 32 + kq * 8 + j];
            }
            p0.u[j] = f2b(v0); p1.u[j] = f2b(v1);
        }
        bw0 = p0.v; bw1 = p1.v;
        if (tid < 12) {
            float s = 0.f;
            if (tid < 11) {
                const float* wp = ws + OFF_WSUF + tid * 512 + hq * 64;
                for (int d = 0; d < 64; ++d) s += ldin(rpb, hq * 64 + d, f32p) * wp[d];
            }
            rpd[tid] = s;
        }
    }

    f32x4 acc[4];
#pragma unroll
    for (int mt = 0; mt < 4; ++mt) acc[mt] = (f32x4){0.f, 0.f, 0.f, 0.f};

    const u16* bp = wf + (tn * 24) * 512 + lane * 8;
    const u16* ap = xf + (ti4 * 4 * 24) * 512 + lane * 8;
#pragma unroll 4
    for (int kc = 0; kc < 24; ++kc) {
        s16x8 bfrag = *(const s16x8*)(bp + kc * 512);
#pragma unroll
        for (int mt = 0; mt < 4; ++mt) {
            s16x8 afrag = *(const s16x8*)(ap + (mt * 24 + kc) * 512);
            acc[mt] = __builtin_amdgcn_mfma_f32_16x16x32_bf16(afrag, bfrag, acc[mt], 0, 0, 0);
        }
    }

    if (isQ) {
#pragma unroll
        for (int mt = 0; mt < 4; ++mt)
#pragma unroll
            for (int r = 0; r < 4; ++r)
                qt[(mt * 16 + quad * 4 + r) * 68 + w * 16 + col] = acc[mt][r] * 0.125f;
        __syncthreads();
        int m = lane & 15, kq = lane >> 4;
#pragma unroll
        for (int kc2 = 0; kc2 < 2; ++kc2) {
            union { u16 u[8]; uint4 v; } pk;
#pragma unroll
            for (int j = 0; j < 8; ++j) {
                int d = kc2 * 32 + kq * 8 + j;
                pk.u[j] = f2b(qt[(w * 16 + m) * 68 + d] + ldin(rcb, hq * 64 + d, f32c));
            }
            *(uint4*)(qf + (((hq * 96 + ti4 * 4 + w) * 2 + kc2) * 512) + lane * 8) = pk.v;
        }
        union { u16 u[8]; s16x8 v; } qa0, qa1;
#pragma unroll
        for (int j = 0; j < 8; ++j) {
            qa0.u[j] = f2b(qt[(w * 16 + m) * 68 + kq * 8 + j]);
            qa1.u[j] = f2b(qt[(w * 16 + m) * 68 + 32 + kq * 8 + j]);
        }
        f32x4 s11a = (f32x4){0.f, 0.f, 0.f, 0.f};
        s11a = __builtin_amdgcn_mfma_f32_16x16x32_bf16(qa0.v, bw0, s11a, 0, 0, 0);
        s11a = __builtin_amdgcn_mfma_f32_16x16x32_bf16(qa1.v, bw1, s11a, 0, 0, 0);
        if (col < 12) {
            float rp = rpd[col];
            float* s11 = ws + OFF_S11;
#pragma unroll
            for (int r = 0; r < 4; ++r)
                s11[(hq * NTOK + i0 + w * 16 + quad * 4 + r) * 12 + col] = s11a[r] + rp;
        }
    } else if (tn < 64) {
        int h = (tn >> 2) - 8;
        int d = ((tn & 3) * 16) + col;
#pragma unroll
        for (int mt = 0; mt < 4; ++mt) {
            int tj = ti4 * 4 + mt;
#pragma unroll
            for (int r = 0; r < 4; ++r) {
                int nn = quad * 4 + r;
                kf[((h * 96 + tj) * 2 + (d >> 5)) * 512 + FIDX(nn, d & 31)] = f2b(acc[mt][r]);
            }
        }
    } else {
        int c = tn * 16 + col - 1024;
        int h = c / 96, d = c % 96;
        int nt = d >> 4, nn = d & 15;
#pragma unroll
        for (int mt = 0; mt < 4; ++mt) {
#pragma unroll
            for (int r = 0; r < 4; ++r) {
                int j = i0 + mt * 16 + quad * 4 + r;
                int jc = j >> 5, kk = j & 31;
                vf[((h * 48 + jc) * 6 + nt) * 512 + FIDX(nn, kk)] = f2b(acc[mt][r]);
            }
        }
    }
}

__global__ __launch_bounds__(256) void qkv_reg(const void* __restrict__ rcb,
                                               const void* __restrict__ rpb,
                                               float* __restrict__ ws) {
    __shared__ float qt[64 * 68];
    __shared__ float rpd[12];
    qkv_body(blockIdx.x, blockIdx.y, rcb, rpb, ws, qt, rpd);
}

// -------- attn phase body (R6 union-LDS version) ---------------------------
struct AttnSh {
    float s11b[192];
    float lw[8][16];
    union {
        alignas(16) u16 pbuf[8][16 * 36];
        float Om[8][16 * 96];
    };
};

__device__ __forceinline__ void attn_body(int h, int ti, float* ws, AttnSh* sh) {
    const u16* qf = (const u16*)(ws + OFF_QF);
    const u16* kf = (const u16*)(ws + OFF_KF);
    const u16* vf = (const u16*)(ws + OFF_VF);
    const float* s11 = ws + OFF_S11;
    u16* aof = (u16*)(ws + OFF_AOF);

    int i0 = ti * 16;
    int tid = threadIdx.x;
    int wv = tid >> 6, lane = tid & 63;
    int quad = lane >> 4, col = lane & 15;

    if (tid < 192) sh->s11b[tid] = s11[(h * NTOK + i0 + tid / 12) * 12 + tid % 12];
    const u16* qp = qf + ((h * 96 + ti) * 2) * 512 + lane * 8;
    s16x8 a_lo = *(const s16x8*)(qp);
    s16x8 a_hi = *(const s16x8*)(qp + 512);
    __syncthreads();

    f32x4 O[6];
    float lsum[4];
#pragma unroll
    for (int nt = 0; nt < 6; ++nt) O[nt] = (f32x4){0.f, 0.f, 0.f, 0.f};
#pragma unroll
    for (int r = 0; r < 4; ++r) lsum[r] = 0.f;

    const u16* kbase = kf + ((h * 96 + wv * 12) * 2) * 512 + lane * 8;
    s16x8 k0lo = *(const s16x8*)(kbase);
    s16x8 k0hi = *(const s16x8*)(kbase + 512);
    s16x8 k1lo = *(const s16x8*)(kbase + 1024);
    s16x8 k1hi = *(const s16x8*)(kbase + 1536);

    for (int c = 0; c < 6; ++c) {
        f32x4 t0 = (f32x4){0.f, 0.f, 0.f, 0.f};
        f32x4 t1 = (f32x4){0.f, 0.f, 0.f, 0.f};
        t0 = __builtin_amdgcn_mfma_f32_16x16x32_bf16(a_lo, k0lo, t0, 0, 0, 0);
        t0 = __builtin_amdgcn_mfma_f32_16x16x32_bf16(a_hi, k0hi, t0, 0, 0, 0);
        t1 = __builtin_amdgcn_mfma_f32_16x16x32_bf16(a_lo, k1lo, t1, 0, 0, 0);
        t1 = __builtin_amdgcn_mfma_f32_16x16x32_bf16(a_hi, k1hi, t1, 0, 0, 0);
        if (c < 5) {
            const u16* kn = kbase + (c + 1) * 2048;
            k0lo = *(const s16x8*)(kn);
            k0hi = *(const s16x8*)(kn + 512);
            k1lo = *(const s16x8*)(kn + 1024);
            k1hi = *(const s16x8*)(kn + 1536);
        }
        int j0 = wv * 192 + c * 32;
        int lo1 = j0 - (i0 + 15), lo2 = i0 - (j0 + 31);
        int dmin = lo1 > 0 ? lo1 : (lo2 > 0 ? lo2 : 0);
        int dm1 = i0 + 15 - j0, dm2 = j0 + 31 - i0;
        int dmax = dm1 > dm2 ? dm1 : dm2;
        int tlo = 31 - __builtin_clz(dmin + 1);
        int thi = 31 - __builtin_clz(dmax + 1);
        if (tlo == thi) {
#pragma unroll
            for (int r = 0; r < 4; ++r) {
                int row = quad * 4 + r;
                float bv = sh->s11b[row * 12 + tlo] - 12.f;
                float p0 = __expf(t0[r] + bv);
                float p1 = __expf(t1[r] + bv);
                sh->pbuf[wv][row * 36 + col] = f2b(p0);
                sh->pbuf[wv][row * 36 + 16 + col] = f2b(p1);
                lsum[r] += p0 + p1;
            }
        } else {
#pragma unroll
            for (int r = 0; r < 4; ++r) {
                int row = quad * 4 + r;
                int ig = i0 + row;
                int d0 = ig - (j0 + col); d0 = d0 < 0 ? -d0 : d0;
                int d1 = ig - (j0 + 16 + col); d1 = d1 < 0 ? -d1 : d1;
                float v0 = t0[r] + sh->s11b[row * 12 + (31 - __builtin_clz(d0 + 1))];
                float v1 = t1[r] + sh->s11b[row * 12 + (31 - __builtin_clz(d1 + 1))];
                float p0 = __expf(v0 - 12.f);
                float p1 = __expf(v1 - 12.f);
                sh->pbuf[wv][row * 36 + col] = f2b(p0);
                sh->pbuf[wv][row * 36 + 16 + col] = f2b(p1);
                lsum[r] += p0 + p1;
            }
        }
        int jc = wv * 6 + c;
        const u16* pr = &sh->pbuf[wv][col * 36 + quad * 8];
        union { s16x8 v; uint2 u2[2]; } pa;
        pa.u2[0] = *(const uint2*)(pr);
        pa.u2[1] = *(const uint2*)(pr + 4);
        const u16* vp = vf + ((h * 48 + jc) * 6) * 512 + lane * 8;
#pragma unroll
        for (int nt = 0; nt < 6; ++nt) {
            s16x8 vfr = *(const s16x8*)(vp + nt * 512);
            O[nt] = __builtin_amdgcn_mfma_f32_16x16x32_bf16(pa.v, vfr, O[nt], 0, 0, 0);
        }
    }

#pragma unroll
    for (int off = 1; off < 16; off <<= 1)
#pragma unroll
        for (int r = 0; r < 4; ++r) lsum[r] += __shfl_xor(lsum[r], off);
    if (col == 0)
#pragma unroll
        for (int r = 0; r < 4; ++r) sh->lw[wv][quad * 4 + r] = lsum[r];
    __syncthreads();   // all waves done with pbuf before Om overwrites it
#pragma unroll
    for (int r = 0; r < 4; ++r) {
        int row = quad * 4 + r;
#pragma unroll
        for (int nt = 0; nt < 6; ++nt)
            sh->Om[wv][row * 96 + nt * 16 + col] = O[nt][r];
    }
    __syncthreads();
    for (int idx = tid; idx < 16 * 96; idx += 512) {
        int row = idx / 96, cc = idx % 96;
        float L = 0.f, val = 0.f;
#pragma unroll
        for (int v = 0; v < 8; ++v) { L += sh->lw[v][row]; val += sh->Om[v][idx]; }
        aof[(ti * 24 + h * 3 + (cc >> 5)) * 512 + FIDX(row, cc & 31)] = f2b(val / L);
    }
}

__global__ __launch_bounds__(512) void attn_mfma(float* __restrict__ ws) {
    __shared__ AttnSh sh;
    attn_body(blockIdx.x & 7, blockIdx.x >> 3, ws, &sh);
}

// -------- out phase body ---------------------------------------------------
__device__ __forceinline__ void out_body256(int ti4, int by, int t2, int f32b,
                                            const void* bout, float* ws,
                                            float* out) {
    const u16* af = (const u16*)(ws + OFF_AOF);
    const u16* wof = (const u16*)(ws + OFF_WOF);
    int lane = t2 & 63, w = t2 >> 6;
    int quad = lane >> 4, col = lane & 15;
    int tn = by * 4 + w;
    int i0 = ti4 * 64;
    int n0 = by * 64;

    f32x4 acc[4];
#pragma unroll
    for (int mt = 0; mt < 4; ++mt) acc[mt] = (f32x4){0.f, 0.f, 0.f, 0.f};

    const u16* bp = wof + (tn * 24) * 512 + lane * 8;
    const u16* ap = af + (ti4 * 4 * 24) * 512 + lane * 8;
#pragma unroll 4
    for (int kc = 0; kc < 24; ++kc) {
        s16x8 bfrag = *(const s16x8*)(bp + kc * 512);
#pragma unroll
        for (int mt = 0; mt < 4; ++mt) {
            s16x8 afrag = *(const s16x8*)(ap + (mt * 24 + kc) * 512);
            acc[mt] = __builtin_amdgcn_mfma_f32_16x16x32_bf16(afrag, bfrag, acc[mt], 0, 0, 0);
        }
    }

    int c = n0 + w * 16 + col;
    float bias = ldin(bout, c, f32b);
#pragma unroll
    for (int mt = 0; mt < 4; ++mt) {
#pragma unroll
        for (int r = 0; r < 4; ++r) {
            int i = i0 + mt * 16 + quad * 4 + r;
            out[i * CDIM + c] = acc[mt][r] + bias;
        }
    }
}

__global__ __launch_bounds__(256) void out_reg(const void* __restrict__ bout,
                                               float* __restrict__ ws,
                                               float* __restrict__ out) {
    int f32b = probe_f32(bout);
    out_body256(blockIdx.x, blockIdx.y, threadIdx.x, f32b, bout, ws, out);
}

// ===========================================================================
// Fused K1: prep units (grid-stride) -> lean barrier -> qkv units.
// Launched COOPERATIVELY (runtime-certified co-residency) with
// grid = min(occ*nCU, 1115); barrier counts blocks (expected = gridDim.x).
// ===========================================================================
__global__ __launch_bounds__(256) void fused_pq2(const void* __restrict__ x,
                                                 const void* __restrict__ Wq,
                                                 const void* __restrict__ Wk,
                                                 const void* __restrict__ Wv,
                                                 const void* __restrict__ Wout,
                                                 const void* __restrict__ Wpos,
                                                 const void* __restrict__ rcb,
                                                 const void* __restrict__ rpb,
                                                 float* __restrict__ ws) {
    __shared__ float qt[64 * 68];
    __shared__ float rpd[12];
    int bid = blockIdx.x;

    for (int u = bid; u < 1115; u += gridDim.x)
        prep_unit(u, x, Wq, Wk, Wv, Wout, Wpos, ws);

    int* c1 = (int*)ws;                 // slots int[0..255]
    gbar_arrive(c1, bid);
    if (bid >= 672) return;             // arrive-only blocks
    gbar_wait(c1, (int)gridDim.x);

    for (int u = bid; u < 672; u += gridDim.x) {
        qkv_body(u % 24, u / 24, rcb, rpb, ws, qt, rpd);
        __syncthreads();                // qt/rpd WAR guard if a block loops
    }
}

// ===========================================================================
// Fused K2: attn units (grid-stride) -> lean barrier -> out units (two
// 256-thread halves per block).  Cooperative launch, grid = min(occ*nCU,768).
// ===========================================================================
__global__ __launch_bounds__(512) void fused_ao2(const void* __restrict__ bout,
                                                 float* __restrict__ ws,
                                                 float* __restrict__ out) {
    __shared__ AttnSh sh;
    int bid = blockIdx.x, tid = threadIdx.x;

    for (int u = bid; u < 768; u += gridDim.x) {
        attn_body(u & 7, u >> 3, ws, &sh);
        __syncthreads();                // sh WAR guard if a block loops
    }

    int* c2 = (int*)ws + 256;           // slots int[256..511]
    gbar_arrive(c2, bid);
    if (bid >= 144) return;             // arrive-only blocks
    gbar_wait(c2, (int)gridDim.x);

    int f32b = probe_f32(bout);
    int half = tid >> 8, t2 = tid & 255;
    for (int u = bid * 2 + half; u < 288; u += gridDim.x * 2)
        out_body256(u % 24, u / 24, t2, f32b, bout, ws, out);
}

// ---------------------------------------------------------------------------
extern "C" void kernel_launch(void* const* d_in, const int* in_sizes, int n_in,
                              void* d_out, int out_size, void* d_ws, size_t ws_size,
                              hipStream_t stream) {
    float* out = (float*)d_out;
    float* ws = (float*)d_ws;

    const int want[9] = {1179648, 393216, 393216, 589824, 589824, 768, 49152, 512, 512};
    int role2in[9], used[9] = {0};
    bool ok = (n_in == 9);
    if (ok) {
        for (int r = 0; r < 9; ++r) {
            int found = -1;
            for (int i = 0; i < 9 && found < 0; ++i)
                if (!used[i] && in_sizes[i] == want[r]) found = i;
            if (found < 0) { ok = false; break; }
            used[found] = 1;
            role2in[r] = found;
        }
    }
    if (!ok) for (int r = 0; r < 9; ++r) role2in[r] = r;

    const void* x    = d_in[role2in[0]];
    const void* Wq   = d_in[role2in[1]];
    const void* Wk   = d_in[role2in[2]];
    const void* Wv   = d_in[role2in[3]];
    const void* Wout = d_in[role2in[4]];
    const void* bout = d_in[role2in[5]];
    const void* Wpos = d_in[role2in[6]];
    const void* rcb  = d_in[role2in[7]];
    const void* rpb  = d_in[role2in[8]];

    // One-time host-side occupancy probe (capture-safe; R1/R5-proven calls).
    static int inited = 0;
    static int G1 = 0, G2 = 0;
    if (!inited) {
        int nCU = 256, occ1 = 0, occ2 = 0;
        hipDeviceProp_t prop;
        int dev = 0;
        (void)hipGetDevice(&dev);
        if (hipGetDeviceProperties(&prop, dev) == hipSuccess && prop.multiProcessorCount > 0)
            nCU = prop.multiProcessorCount;
        if (hipOccupancyMaxActiveBlocksPerMultiprocessor(&occ1, fused_pq2, 256, 0) == hipSuccess
            && occ1 > 0) {
            G1 = occ1 * nCU; if (G1 > 1115) G1 = 1115;
            if (G1 < 672) G1 = 0;       // need single-pass qkv phase
        }
        if (hipOccupancyMaxActiveBlocksPerMultiprocessor(&occ2, fused_ao2, 512, 0) == hipSuccess
            && occ2 > 0) {
            G2 = occ2 * nCU; if (G2 > 768) G2 = 768;
            if (G2 < 288) G2 = 0;       // need single-pass out phase
        }
        inited = 1;
    }

    if (G1 > 0 || G2 > 0)
        hipMemsetAsync(d_ws, 0, 4096, stream);   // zero barrier counters

    bool doneA = false, doneB = false;
    if (G1 > 0) {
        void* argsA[] = {(void*)&x, (void*)&Wq, (void*)&Wk, (void*)&Wv, (void*)&Wout,
                         (void*)&Wpos, (void*)&rcb, (void*)&rpb, (void*)&ws};
        doneA = hipLaunchCooperativeKernel(fused_pq2, dim3(G1), dim3(256),
                                           argsA, 0, stream) == hipSuccess;
    }
    if (!doneA) {
        hipLaunchKernelGGL(prep, dim3(1115), dim3(256), 0, stream,
                           x, Wq, Wk, Wv, Wout, Wpos, ws);
        hipLaunchKernelGGL(qkv_reg, dim3(24, 28), dim3(256), 0, stream,
                           rcb, rpb, ws);
    }
    if (G2 > 0) {
        void* argsB[] = {(void*)&bout, (void*)&ws, (void*)&out};
        doneB = hipLaunchCooperativeKernel(fused_ao2, dim3(G2), dim3(512),
                                           argsB, 0, stream) == hipSuccess;
    }
    if (!doneB) {
        hipLaunchKernelGGL(attn_mfma, dim3(768), dim3(512), 0, stream, ws);
        hipLaunchKernelGGL(out_reg, dim3(24, 12), dim3(256), 0, stream,
                           bout, ws, out);
    }
}

// Round 9
// 143.010 us; speedup vs baseline: 1.8008x; 1.0293x over previous
//
#include <hip/hip_runtime.h>
#include <stdint.h>

#define NTOK 1536
#define CDIM 768
#define NH 8
#define DKH 64
#define DVH 96
#define NF 96

typedef unsigned short u16;
typedef __attribute__((ext_vector_type(8))) short s16x8;   // 8 bf16 (4 VGPRs)
typedef __attribute__((ext_vector_type(4))) float f32x4;   // MFMA acc

__device__ __forceinline__ float b2f(u16 u) {
    union { uint32_t i; float f; } v; v.i = ((uint32_t)u) << 16; return v.f;
}
__device__ __forceinline__ u16 f2b(float f) {
    union { float f; uint32_t i; } v; v.f = f;
    uint32_t x = v.i;
    return (u16)((x + 0x7FFFu + ((x >> 16) & 1u)) >> 16);
}
__device__ __forceinline__ float ldin(const void* p, int i, int f32) {
    return f32 ? ((const float*)p)[i] : b2f(((const u16*)p)[i]);
}

// Inline wave-uniform dtype probe: scans first 256 u16 words.  A true-bf16
// buffer never decodes |v|>=1e6; fp32 mantissa-low words do w.p. ~0.42 each
// (~128 of the 256 samples) -> miss prob ~3e-29.  Returns 1 iff fp32.
__device__ __forceinline__ int probe_f32(const void* p) {
    const u16* a = (const u16*)p;
    int lane = threadIdx.x & 63;
    int bad = 0;
#pragma unroll
    for (int t = 0; t < 4; ++t) {
        float v = b2f(a[lane + t * 64]);
        if (!(fabsf(v) < 1e6f)) bad = 1;
    }
    return __ballot(bad) != 0ull;
}

// Fragment-major: element (m, kk) of a (16 x 32k) 512-elem block sits at
// ((kk>>3)*16 + m)*8 + (kk&7)  == lane*8 + slot.
#define FIDX(m, kk) ((((kk) >> 3) * 16 + (m)) * 8 + ((kk) & 7))

// ---------------------------------------------------------------------------
// ws layout (float offsets). ~14.8 MB.
// ---------------------------------------------------------------------------
#define OFF_WSUF 16
#define OFF_S11  (OFF_WSUF + 5632)
#define OFF_QF   (OFF_S11 + 147456)     // u16: qfrag  (h,ti:96,kc2:2)  A-frags
#define OFF_KF   (OFF_QF + 393216)      // u16: kfrag  (h,tj:96,kc2:2)  B-frags
#define OFF_VF   (OFF_KF + 393216)      // u16: vfrag  (h,jc:48,nt:6)   B-frags
#define OFF_AOF  (OFF_VF + 589824)      // u16: aofrag (ti:96,kc:24)    A-frags
#define OFF_XF   (OFF_AOF + 589824)     // u16: xfrag  (ti:96,kc:24)    A-frags
#define OFF_WF   (OFF_XF + 589824)      // u16: wfrag  (tn:112,kc:24)   B-frags
#define OFF_WOF  (OFF_WF + 688128)      // u16: wofrag (tn:48,kc:24)    B-frags

// ---------------------------------------------------------------------------
// Kernel PR: build fragment buffers.  NO LDS, NO barriers, high MLP.
// R9 change: wsuf units (heaviest, 196KB reads each) moved FIRST (bx 0-10)
// so they don't serialize the kernel tail.
// ---------------------------------------------------------------------------
__global__ __launch_bounds__(256) void prep(const void* __restrict__ x,
                                            const void* __restrict__ Wq,
                                            const void* __restrict__ Wk,
                                            const void* __restrict__ Wv,
                                            const void* __restrict__ Wout,
                                            const void* __restrict__ Wpos,
                                            float* __restrict__ ws) {
    int bx = blockIdx.x, tid = threadIdx.x;
    int wv = tid >> 6, L = tid & 63;

    if (bx < 11) {
        // ---- wsuf (launched first: largest per-block work) ----
        int t = bx;
        int f = probe_f32(Wpos);
        for (int hd = tid; hd < 512; hd += 256) {
            float s0 = 0.f, s1 = 0.f, s2 = 0.f, s3 = 0.f;
            int f0 = t;
            for (; f0 + 4 <= NF; f0 += 4) {
                s0 += ldin(Wpos, f0 * 512 + hd, f);
                s1 += ldin(Wpos, (f0 + 1) * 512 + hd, f);
                s2 += ldin(Wpos, (f0 + 2) * 512 + hd, f);
                s3 += ldin(Wpos, (f0 + 3) * 512 + hd, f);
            }
            for (; f0 < NF; ++f0) s0 += ldin(Wpos, f0 * 512 + hd, f);
            ws[OFF_WSUF + t * 512 + hd] = (s0 + s1) + (s2 + s3);
        }
        return;
    }
    if (bx < 155) {
        int bxa = bx - 11;
        int f = probe_f32(x);
        u16* dst = (u16*)(ws + OFF_XF);
        int cbase = (bxa * 4 + wv) * 4;
        int m = L & 15, kq = L >> 4;
        int srcs[4];
#pragma unroll
        for (int c = 0; c < 4; ++c) {
            int ch = cbase + c;
            int ti = ch / 24, kc = ch % 24;
            srcs[c] = (ti * 16 + m) * CDIM + kc * 32 + kq * 8;
        }
        if (f) {
            float4 a[4][2];
#pragma unroll
            for (int c = 0; c < 4; ++c) {
                const float* xp = (const float*)x + srcs[c];
                a[c][0] = *(const float4*)(xp);
                a[c][1] = *(const float4*)(xp + 4);
            }
#pragma unroll
            for (int c = 0; c < 4; ++c) {
                union { u16 u[8]; uint4 v; } pk;
                pk.u[0] = f2b(a[c][0].x); pk.u[1] = f2b(a[c][0].y);
                pk.u[2] = f2b(a[c][0].z); pk.u[3] = f2b(a[c][0].w);
                pk.u[4] = f2b(a[c][1].x); pk.u[5] = f2b(a[c][1].y);
                pk.u[6] = f2b(a[c][1].z); pk.u[7] = f2b(a[c][1].w);
                *(uint4*)(dst + (cbase + c) * 512 + L * 8) = pk.v;
            }
        } else {
            uint4 v[4];
#pragma unroll
            for (int c = 0; c < 4; ++c) v[c] = *(const uint4*)((const u16*)x + srcs[c]);
#pragma unroll
            for (int c = 0; c < 4; ++c)
                *(uint4*)(dst + (cbase + c) * 512 + L * 8) = v[c];
        }
        return;
    }
    {
        int c = (bx - 155) * 4 + wv;
        const void* src; int ld, cn0; u16* dst; int kc;
        if (c < 2688) {
            int tn = c / 24; kc = c % 24;
            int n0 = tn * 16;
            dst = (u16*)(ws + OFF_WF) + c * 512;
            if (n0 < 512)       { src = Wq; ld = 512;  cn0 = n0; }
            else if (n0 < 1024) { src = Wk; ld = 512;  cn0 = n0 - 512; }
            else                { src = Wv; ld = CDIM; cn0 = n0 - 1024; }
        } else {
            int c2 = c - 2688;
            int tn = c2 / 24; kc = c2 % 24;
            dst = (u16*)(ws + OFF_WOF) + c2 * 512;
            src = Wout; ld = CDIM; cn0 = tn * 16;
        }
        int f = probe_f32(src);
        int nn = L & 15, kq = L >> 4;
        int base = (kc * 32 + kq * 8) * ld + cn0 + nn;
        union { u16 u[8]; uint4 v; } pk;
        if (f) {
            const float* sp = (const float*)src + base;
            float a0 = sp[0], a1 = sp[ld], a2 = sp[2 * ld], a3 = sp[3 * ld];
            float a4 = sp[4 * ld], a5 = sp[5 * ld], a6 = sp[6 * ld], a7 = sp[7 * ld];
            pk.u[0] = f2b(a0); pk.u[1] = f2b(a1); pk.u[2] = f2b(a2); pk.u[3] = f2b(a3);
            pk.u[4] = f2b(a4); pk.u[5] = f2b(a5); pk.u[6] = f2b(a6); pk.u[7] = f2b(a7);
        } else {
            const u16* sp = (const u16*)src + base;
            pk.u[0] = sp[0]; pk.u[1] = sp[ld]; pk.u[2] = sp[2 * ld]; pk.u[3] = sp[3 * ld];
            pk.u[4] = sp[4 * ld]; pk.u[5] = sp[5 * ld]; pk.u[6] = sp[6 * ld]; pk.u[7] = sp[7 * ld];
        }
        *(uint4*)(dst + L * 8) = pk.v;
    }
}

// ---------------------------------------------------------------------------
// Kernel 1: QKV GEMM, register-direct MFMA.  R9 change: the rpd dot product
// (12-thread serial 64-iter chain, a ~multi-us tail on wave 0 of isQ blocks)
// is 4-way unrolled into independent accumulator chains (4x load MLP).
// ---------------------------------------------------------------------------
__global__ __launch_bounds__(256) void qkv_reg(const void* __restrict__ rcb,
                                               const void* __restrict__ rpb,
                                               float* __restrict__ ws) {
    __shared__ float qt[64 * 68];
    __shared__ float rpd[12];
    const u16* xf = (const u16*)(ws + OFF_XF);
    const u16* wf = (const u16*)(ws + OFF_WF);
    u16* qf = (u16*)(ws + OFF_QF);
    u16* kf = (u16*)(ws + OFF_KF);
    u16* vf = (u16*)(ws + OFF_VF);

    int tid = threadIdx.x;
    int lane = tid & 63, w = tid >> 6;
    int quad = lane >> 4, col = lane & 15;
    int ti4 = blockIdx.x;
    int tn4 = blockIdx.y;
    int tn = tn4 * 4 + w;
    int i0 = ti4 * 64;
    bool isQ = (tn4 < 8);
    int hq = tn4;

    s16x8 bw0, bw1;
    int f32p = 0, f32c = 0;
    if (isQ) {
        f32p = probe_f32(rpb);
        f32c = probe_f32(rcb);
        int t = lane & 15, kq = lane >> 4;
        union { u16 u[8]; s16x8 v; } p0, p1;
#pragma unroll
        for (int j = 0; j < 8; ++j) {
            float v0 = 0.f, v1 = 0.f;
            if (t < 11) {
                v0 = ws[OFF_WSUF + t * 512 + hq * 64 + kq * 8 + j];
                v1 = ws[OFF_WSUF + t * 512 + hq * 64 + 32 + kq * 8 + j];
            }
            p0.u[j] = f2b(v0); p1.u[j] = f2b(v1);
        }
        bw0 = p0.v; bw1 = p1.v;
        if (tid < 12) {
            float s0 = 0.f, s1 = 0.f, s2 = 0.f, s3 = 0.f;
            if (tid < 11) {
                const float* wp = ws + OFF_WSUF + tid * 512 + hq * 64;
#pragma unroll 4
                for (int d = 0; d < 64; d += 4) {
                    s0 += ldin(rpb, hq * 64 + d,     f32p) * wp[d];
                    s1 += ldin(rpb, hq * 64 + d + 1, f32p) * wp[d + 1];
                    s2 += ldin(rpb, hq * 64 + d + 2, f32p) * wp[d + 2];
                    s3 += ldin(rpb, hq * 64 + d + 3, f32p) * wp[d + 3];
                }
            }
            rpd[tid] = (s0 + s1) + (s2 + s3);
        }
    }

    f32x4 acc[4];
#pragma unroll
    for (int mt = 0; mt < 4; ++mt) acc[mt] = (f32x4){0.f, 0.f, 0.f, 0.f};

    const u16* bp = wf + (tn * 24) * 512 + lane * 8;
    const u16* ap = xf + (ti4 * 4 * 24) * 512 + lane * 8;
#pragma unroll 4
    for (int kc = 0; kc < 24; ++kc) {
        s16x8 bfrag = *(const s16x8*)(bp + kc * 512);
#pragma unroll
        for (int mt = 0; mt < 4; ++mt) {
            s16x8 afrag = *(const s16x8*)(ap + (mt * 24 + kc) * 512);
            acc[mt] = __builtin_amdgcn_mfma_f32_16x16x32_bf16(afrag, bfrag, acc[mt], 0, 0, 0);
        }
    }

    if (isQ) {
#pragma unroll
        for (int mt = 0; mt < 4; ++mt)
#pragma unroll
            for (int r = 0; r < 4; ++r)
                qt[(mt * 16 + quad * 4 + r) * 68 + w * 16 + col] = acc[mt][r] * 0.125f;
        __syncthreads();
        int m = lane & 15, kq = lane >> 4;
#pragma unroll
        for (int kc2 = 0; kc2 < 2; ++kc2) {
            union { u16 u[8]; uint4 v; } pk;
#pragma unroll
            for (int j = 0; j < 8; ++j) {
                int d = kc2 * 32 + kq * 8 + j;
                pk.u[j] = f2b(qt[(w * 16 + m) * 68 + d] + ldin(rcb, hq * 64 + d, f32c));
            }
            *(uint4*)(qf + (((hq * 96 + ti4 * 4 + w) * 2 + kc2) * 512) + lane * 8) = pk.v;
        }
        union { u16 u[8]; s16x8 v; } qa0, qa1;
#pragma unroll
        for (int j = 0; j < 8; ++j) {
            qa0.u[j] = f2b(qt[(w * 16 + m) * 68 + kq * 8 + j]);
            qa1.u[j] = f2b(qt[(w * 16 + m) * 68 + 32 + kq * 8 + j]);
        }
        f32x4 s11a = (f32x4){0.f, 0.f, 0.f, 0.f};
        s11a = __builtin_amdgcn_mfma_f32_16x16x32_bf16(qa0.v, bw0, s11a, 0, 0, 0);
        s11a = __builtin_amdgcn_mfma_f32_16x16x32_bf16(qa1.v, bw1, s11a, 0, 0, 0);
        if (col < 12) {
            float rp = rpd[col];
            float* s11 = ws + OFF_S11;
#pragma unroll
            for (int r = 0; r < 4; ++r)
                s11[(hq * NTOK + i0 + w * 16 + quad * 4 + r) * 12 + col] = s11a[r] + rp;
        }
    } else if (tn < 64) {
        int h = (tn >> 2) - 8;
        int d = ((tn & 3) * 16) + col;
#pragma unroll
        for (int mt = 0; mt < 4; ++mt) {
            int tj = ti4 * 4 + mt;
#pragma unroll
            for (int r = 0; r < 4; ++r) {
                int nn = quad * 4 + r;
                kf[((h * 96 + tj) * 2 + (d >> 5)) * 512 + FIDX(nn, d & 31)] = f2b(acc[mt][r]);
            }
        }
    } else {
        int c = tn * 16 + col - 1024;
        int h = c / 96, d = c % 96;
        int nt = d >> 4, nn = d & 15;
#pragma unroll
        for (int mt = 0; mt < 4; ++mt) {
#pragma unroll
            for (int r = 0; r < 4; ++r) {
                int j = i0 + mt * 16 + quad * 4 + r;
                int jc = j >> 5, kk = j & 31;
                vf[((h * 48 + jc) * 6 + nt) * 512 + FIDX(nn, kk)] = f2b(acc[mt][r]);
            }
        }
    }
}

// ---------------------------------------------------------------------------
// Kernel 3: MFMA flash attention (R6 union-LDS).  R9 change: V-fragment
// loads hoisted above the exp/bias block so their L2 latency hides under
// the VALU work (pure-read motion; no semantic change).
// ---------------------------------------------------------------------------
__global__ __launch_bounds__(512) void attn_mfma(float* __restrict__ ws) {
    __shared__ float s11b[192];
    __shared__ float lw[8][16];
    __shared__ union {
        alignas(16) u16 pbuf[8][16 * 36];
        float Om[8][16 * 96];
    } sh;

    const u16* qf = (const u16*)(ws + OFF_QF);
    const u16* kf = (const u16*)(ws + OFF_KF);
    const u16* vf = (const u16*)(ws + OFF_VF);
    const float* s11 = ws + OFF_S11;
    u16* aof = (u16*)(ws + OFF_AOF);

    int h = blockIdx.x & 7;               // XCD-affine
    int ti = blockIdx.x >> 3;
    int i0 = ti * 16;
    int tid = threadIdx.x;
    int wv = tid >> 6, lane = tid & 63;
    int quad = lane >> 4, col = lane & 15;

    if (tid < 192) s11b[tid] = s11[(h * NTOK + i0 + tid / 12) * 12 + tid % 12];
    const u16* qp = qf + ((h * 96 + ti) * 2) * 512 + lane * 8;
    s16x8 a_lo = *(const s16x8*)(qp);
    s16x8 a_hi = *(const s16x8*)(qp + 512);
    __syncthreads();

    f32x4 O[6];
    float lsum[4];
#pragma unroll
    for (int nt = 0; nt < 6; ++nt) O[nt] = (f32x4){0.f, 0.f, 0.f, 0.f};
#pragma unroll
    for (int r = 0; r < 4; ++r) lsum[r] = 0.f;

    // prefetch chunk 0 K-frags
    const u16* kbase = kf + ((h * 96 + wv * 12) * 2) * 512 + lane * 8;
    s16x8 k0lo = *(const s16x8*)(kbase);
    s16x8 k0hi = *(const s16x8*)(kbase + 512);
    s16x8 k1lo = *(const s16x8*)(kbase + 1024);
    s16x8 k1hi = *(const s16x8*)(kbase + 1536);

    for (int c = 0; c < 6; ++c) {
        // ---- QK^T with current K regs ----
        f32x4 t0 = (f32x4){0.f, 0.f, 0.f, 0.f};
        f32x4 t1 = (f32x4){0.f, 0.f, 0.f, 0.f};
        t0 = __builtin_amdgcn_mfma_f32_16x16x32_bf16(a_lo, k0lo, t0, 0, 0, 0);
        t0 = __builtin_amdgcn_mfma_f32_16x16x32_bf16(a_hi, k0hi, t0, 0, 0, 0);
        t1 = __builtin_amdgcn_mfma_f32_16x16x32_bf16(a_lo, k1lo, t1, 0, 0, 0);
        t1 = __builtin_amdgcn_mfma_f32_16x16x32_bf16(a_hi, k1hi, t1, 0, 0, 0);
        // ---- prefetch next chunk's K frags ----
        if (c < 5) {
            const u16* kn = kbase + (c + 1) * 2048;
            k0lo = *(const s16x8*)(kn);
            k0hi = *(const s16x8*)(kn + 512);
            k1lo = *(const s16x8*)(kn + 1024);
            k1hi = *(const s16x8*)(kn + 1536);
        }
        // ---- V-fragment loads issued early (latency hides under exp) ----
        int jc = wv * 6 + c;
        const u16* vp = vf + ((h * 48 + jc) * 6) * 512 + lane * 8;
        s16x8 vr[6];
#pragma unroll
        for (int nt = 0; nt < 6; ++nt) vr[nt] = *(const s16x8*)(vp + nt * 512);
        // ---- bias + exp(s-12) + store P ----
        int j0 = wv * 192 + c * 32;
        int lo1 = j0 - (i0 + 15), lo2 = i0 - (j0 + 31);
        int dmin = lo1 > 0 ? lo1 : (lo2 > 0 ? lo2 : 0);
        int dm1 = i0 + 15 - j0, dm2 = j0 + 31 - i0;
        int dmax = dm1 > dm2 ? dm1 : dm2;
        int tlo = 31 - __builtin_clz(dmin + 1);
        int thi = 31 - __builtin_clz(dmax + 1);
        if (tlo == thi) {
#pragma unroll
            for (int r = 0; r < 4; ++r) {
                int row = quad * 4 + r;
                float bv = s11b[row * 12 + tlo] - 12.f;
                float p0 = __expf(t0[r] + bv);
                float p1 = __expf(t1[r] + bv);
                sh.pbuf[wv][row * 36 + col] = f2b(p0);
                sh.pbuf[wv][row * 36 + 16 + col] = f2b(p1);
                lsum[r] += p0 + p1;
            }
        } else {
#pragma unroll
            for (int r = 0; r < 4; ++r) {
                int row = quad * 4 + r;
                int ig = i0 + row;
                int d0 = ig - (j0 + col); d0 = d0 < 0 ? -d0 : d0;
                int d1 = ig - (j0 + 16 + col); d1 = d1 < 0 ? -d1 : d1;
                float v0 = t0[r] + s11b[row * 12 + (31 - __builtin_clz(d0 + 1))];
                float v1 = t1[r] + s11b[row * 12 + (31 - __builtin_clz(d1 + 1))];
                float p0 = __expf(v0 - 12.f);
                float p1 = __expf(v1 - 12.f);
                sh.pbuf[wv][row * 36 + col] = f2b(p0);
                sh.pbuf[wv][row * 36 + 16 + col] = f2b(p1);
                lsum[r] += p0 + p1;
            }
        }
        // ---- PV (compiler inserts lgkmcnt for the pbuf RAW) ----
        const u16* pr = &sh.pbuf[wv][col * 36 + quad * 8];
        union { s16x8 v; uint2 u2[2]; } pa;
        pa.u2[0] = *(const uint2*)(pr);
        pa.u2[1] = *(const uint2*)(pr + 4);
#pragma unroll
        for (int nt = 0; nt < 6; ++nt)
            O[nt] = __builtin_amdgcn_mfma_f32_16x16x32_bf16(pa.v, vr[nt], O[nt], 0, 0, 0);
    }

#pragma unroll
    for (int off = 1; off < 16; off <<= 1)
#pragma unroll
        for (int r = 0; r < 4; ++r) lsum[r] += __shfl_xor(lsum[r], off);
    if (col == 0)
#pragma unroll
        for (int r = 0; r < 4; ++r) lw[wv][quad * 4 + r] = lsum[r];
    __syncthreads();   // all waves done with pbuf before Om overwrites it
#pragma unroll
    for (int r = 0; r < 4; ++r) {
        int row = quad * 4 + r;
#pragma unroll
        for (int nt = 0; nt < 6; ++nt)
            sh.Om[wv][row * 96 + nt * 16 + col] = O[nt][r];
    }
    __syncthreads();
    for (int idx = tid; idx < 16 * 96; idx += 512) {
        int row = idx / 96, cc = idx % 96;
        float L = 0.f, val = 0.f;
#pragma unroll
        for (int v = 0; v < 8; ++v) { L += lw[v][row]; val += sh.Om[v][idx]; }
        aof[(ti * 24 + h * 3 + (cc >> 5)) * 512 + FIDX(row, cc & 31)] = f2b(val / L);
    }
}

// ---------------------------------------------------------------------------
// Kernel 4: output GEMM, register-direct MFMA (R0-proven version, verbatim).
// ---------------------------------------------------------------------------
__global__ __launch_bounds__(256) void out_reg(const void* __restrict__ bout,
                                               float* __restrict__ ws,
                                               float* __restrict__ out) {
    const u16* af = (const u16*)(ws + OFF_AOF);
    const u16* wof = (const u16*)(ws + OFF_WOF);
    int f32b = probe_f32(bout);

    int tid = threadIdx.x;
    int lane = tid & 63, w = tid >> 6;
    int quad = lane >> 4, col = lane & 15;
    int ti4 = blockIdx.x;
    int tn = blockIdx.y * 4 + w;
    int i0 = ti4 * 64;
    int n0 = blockIdx.y * 64;

    f32x4 acc[4];
#pragma unroll
    for (int mt = 0; mt < 4; ++mt) acc[mt] = (f32x4){0.f, 0.f, 0.f, 0.f};

    const u16* bp = wof + (tn * 24) * 512 + lane * 8;
    const u16* ap = af + (ti4 * 4 * 24) * 512 + lane * 8;
#pragma unroll 4
    for (int kc = 0; kc < 24; ++kc) {
        s16x8 bfrag = *(const s16x8*)(bp + kc * 512);
#pragma unroll
        for (int mt = 0; mt < 4; ++mt) {
            s16x8 afrag = *(const s16x8*)(ap + (mt * 24 + kc) * 512);
            acc[mt] = __builtin_amdgcn_mfma_f32_16x16x32_bf16(afrag, bfrag, acc[mt], 0, 0, 0);
        }
    }

    int c = n0 + w * 16 + col;
    float bias = ldin(bout, c, f32b);
#pragma unroll
    for (int mt = 0; mt < 4; ++mt) {
#pragma unroll
        for (int r = 0; r < 4; ++r) {
            int i = i0 + mt * 16 + quad * 4 + r;
            out[i * CDIM + c] = acc[mt][r] + bias;
        }
    }
}

// ---------------------------------------------------------------------------
extern "C" void kernel_launch(void* const* d_in, const int* in_sizes, int n_in,
                              void* d_out, int out_size, void* d_ws, size_t ws_size,
                              hipStream_t stream) {
    float* out = (float*)d_out;
    float* ws = (float*)d_ws;

    const int want[9] = {1179648, 393216, 393216, 589824, 589824, 768, 49152, 512, 512};
    int role2in[9], used[9] = {0};
    bool ok = (n_in == 9);
    if (ok) {
        for (int r = 0; r < 9; ++r) {
            int found = -1;
            for (int i = 0; i < 9 && found < 0; ++i)
                if (!used[i] && in_sizes[i] == want[r]) found = i;
            if (found < 0) { ok = false; break; }
            used[found] = 1;
            role2in[r] = found;
        }
    }
    if (!ok) for (int r = 0; r < 9; ++r) role2in[r] = r;

    const void* x    = d_in[role2in[0]];
    const void* Wq   = d_in[role2in[1]];
    const void* Wk   = d_in[role2in[2]];
    const void* Wv   = d_in[role2in[3]];
    const void* Wout = d_in[role2in[4]];
    const void* bout = d_in[role2in[5]];
    const void* Wpos = d_in[role2in[6]];
    const void* rcb  = d_in[role2in[7]];
    const void* rpb  = d_in[role2in[8]];

    hipLaunchKernelGGL(prep, dim3(1115), dim3(256), 0, stream,
                       x, Wq, Wk, Wv, Wout, Wpos, ws);
    hipLaunchKernelGGL(qkv_reg, dim3(24, 28), dim3(256), 0, stream,
                       rcb, rpb, ws);
    hipLaunchKernelGGL(attn_mfma, dim3(768), dim3(512), 0, stream, ws);
    hipLaunchKernelGGL(out_reg, dim3(24, 12), dim3(256), 0, stream,
                       bout, ws, out);
}